// Round 12
// baseline (515.808 us; speedup 1.0000x reference)
//
#include <hip/hip_runtime.h>
#include <math.h>

#define BB 16
#define CC 512
#define LL 1024
#define NHEAD 8
#define DH 64
#define KW 7

typedef unsigned short us;
typedef unsigned short us8 __attribute__((ext_vector_type(8)));
typedef unsigned short us4 __attribute__((ext_vector_type(4)));
typedef short mbf8 __attribute__((ext_vector_type(8)));
typedef float f32x4 __attribute__((ext_vector_type(4)));
typedef float f32x16 __attribute__((ext_vector_type(16)));

#define QSCALE 0.18033688f  /* 0.125 * log2(e) */

__device__ inline us f2bf(float f) {
  union { float f; unsigned int u; } v; v.f = f;
  unsigned int u = v.u;
  u += 0x7fffu + ((u >> 16) & 1u);
  return (us)(u >> 16);
}
__device__ inline float bf2f(us s) {
  union { unsigned int u; float f; } v; v.u = ((unsigned int)s) << 16;
  return v.f;
}
__device__ __forceinline__ float fexp2(float x) {
  float r;
  asm("v_exp_f32 %0, %1" : "=v"(r) : "v"(x));
  return r;
}

// global -> LDS direct 16B copy
__device__ __forceinline__ void gld16(const void* g, void* l) {
  __builtin_amdgcn_global_load_lds(
      (__attribute__((address_space(1))) unsigned int*)(uintptr_t)(g),
      (__attribute__((address_space(3))) unsigned int*)(unsigned int)(uintptr_t)(l),
      16, 0, 0);
}

// ---- weight fp32 -> bf16 pre-convert, 9 regions of CC*CC ----
// [0..4):pw_w  [4):w_kv K-rows  [5):w_q * QSCALE  [6):w_kv V-rows  [7):ffd1 [8):ffd2
__global__ __launch_bounds__(256) void k_cvtW(const float* __restrict__ pw,
                                              const float* __restrict__ wkv,
                                              const float* __restrict__ wq,
                                              const float* __restrict__ wf1,
                                              const float* __restrict__ wf2,
                                              us* __restrict__ dst) {
  int idx = blockIdx.x * 256 + threadIdx.x;
  int e = idx * 4;
  const int n2 = CC * CC;
  int r = e / n2, o = e - r * n2;
  const float* src; float sc = 1.0f;
  if (r < 4)       { src = pw + e; }
  else if (r == 4) { src = wkv + o; }
  else if (r == 5) { src = wq + o; sc = QSCALE; }
  else if (r == 6) { src = wkv + n2 + o; }
  else if (r == 7) { src = wf1 + o; }
  else             { src = wf2 + o; }
  float4 v = *(const float4*)src;
  us4 ov; ov[0] = f2bf(v.x * sc); ov[1] = f2bf(v.y * sc);
  ov[2] = f2bf(v.z * sc); ov[3] = f2bf(v.w * sc);
  *(us4*)(dst + e) = ov;
}

// ---- x (B,C,L) f32 -> Act (B,L,C) bf16 with timing signal ----
__global__ __launch_bounds__(256) void k_in_tr(const float* __restrict__ x,
                                               us* __restrict__ act) {
  __shared__ float xt[64][69];
  int t = threadIdx.x;
  int c0 = blockIdx.x * 64;
  int l0 = blockIdx.y * 64;
  int b  = blockIdx.z;
  {
    int r = t >> 2, lo2 = (t & 3) * 16;
    const float* src = x + ((size_t)b * CC + c0 + r) * LL + l0 + lo2;
#pragma unroll
    for (int q = 0; q < 4; ++q) {
      float4 v = *(const float4*)(src + q * 4);
      xt[r][lo2 + q * 4 + 0] = v.x; xt[r][lo2 + q * 4 + 1] = v.y;
      xt[r][lo2 + q * 4 + 2] = v.z; xt[r][lo2 + q * 4 + 3] = v.w;
    }
  }
  __syncthreads();
  const float log_inc = 9.210340371976184f / 255.0f;
  int lr = t >> 2, co = (t & 3) * 16;
  int l = l0 + lr;
  us obuf[16];
#pragma unroll
  for (int u = 0; u < 16; ++u) {
    int c = c0 + co + u;
    float inv = __expf(-(float)(c & 255) * log_inc);
    float st = (float)l * inv;
    float sg = (c < 256) ? sinf(st) : cosf(st);
    obuf[u] = f2bf(xt[co + u][lr] + sg);
  }
  us* dst = act + ((size_t)b * LL + l) * CC + c0 + co;
  *(us8*)dst = *(us8*)&obuf[0];
  *(us8*)(dst + 8) = *(us8*)&obuf[8];
}

// ---- row LayerNorm over C, (B,L,C) bf16 ----
__global__ __launch_bounds__(256) void k_ln(const us* __restrict__ in,
                                            const float* __restrict__ g,
                                            const float* __restrict__ bta,
                                            us* __restrict__ out) {
  int t = threadIdx.x;
  int lane = t & 63, w = t >> 6;
  size_t row = (size_t)blockIdx.x * 4 + w;
  const us* p = in + row * CC + lane * 8;
  us8 v = *(const us8*)p;
  float f[8]; float s = 0.f, ss = 0.f;
#pragma unroll
  for (int i = 0; i < 8; ++i) { f[i] = bf2f(v[i]); s += f[i]; ss += f[i] * f[i]; }
#pragma unroll
  for (int m = 1; m < 64; m <<= 1) { s += __shfl_xor(s, m); ss += __shfl_xor(ss, m); }
  float mean = s * (1.f / CC);
  float rstd = rsqrtf(ss * (1.f / CC) - mean * mean + 1e-5f);
  float4 g0 = *(const float4*)(g + lane * 8), g1 = *(const float4*)(g + lane * 8 + 4);
  float4 b0 = *(const float4*)(bta + lane * 8), b1 = *(const float4*)(bta + lane * 8 + 4);
  float gg[8] = {g0.x, g0.y, g0.z, g0.w, g1.x, g1.y, g1.z, g1.w};
  float bb2[8] = {b0.x, b0.y, b0.z, b0.w, b1.x, b1.y, b1.z, b1.w};
  us o[8];
#pragma unroll
  for (int i = 0; i < 8; ++i) o[i] = f2bf((f[i] - mean) * rstd * gg[i] + bb2[i]);
  *(us8*)(out + row * CC + lane * 8) = *(us8*)&o[0];
}

// ---- fused LayerNorm + depthwise conv K=7 along L, (B,L,C) bf16 ----
__global__ __launch_bounds__(256) void k_lndw(const us* __restrict__ in,
                                              const float* __restrict__ g,
                                              const float* __restrict__ bln,
                                              const float* __restrict__ w,
                                              us* __restrict__ out) {
  __shared__ float wld[KW * CC];
  __shared__ float stm[12], str[12];
  int t = threadIdx.x;
  int lane = t & 63, wv = t >> 6;
  for (int i = t; i < CC * KW; i += 256) {
    int j = i >> 9, c2 = i & (CC - 1);
    wld[i] = w[c2 * KW + j];
  }
  int rowid = blockIdx.x * 4;
  int l0 = rowid & (LL - 1);
  int b = rowid >> 10;
#pragma unroll
  for (int rr = 0; rr < 3; ++rr) {
    int slot = rr * 4 + wv;
    int r = l0 - 3 + slot;
    float mean = 0.f, rstd = 0.f;
    if (r >= 0 && r < LL) {
      us8 v = *(const us8*)(in + ((size_t)b * LL + r) * CC + lane * 8);
      float s = 0.f, ss = 0.f;
#pragma unroll
      for (int i = 0; i < 8; ++i) { float f = bf2f(v[i]); s += f; ss += f * f; }
#pragma unroll
      for (int m = 1; m < 64; m <<= 1) { s += __shfl_xor(s, m); ss += __shfl_xor(ss, m); }
      mean = s * (1.f / CC);
      rstd = rsqrtf(ss * (1.f / CC) - mean * mean + 1e-5f);
    }
    if (lane == 0) { stm[slot] = mean; str[slot] = rstd; }
  }
  __syncthreads();
  int c = lane * 8;
  int l = l0 + wv;
  float acc[8] = {}, ws[8] = {};
#pragma unroll
  for (int j = 0; j < KW; ++j) {
    int lj = l + j - 3;
    if (lj < 0 || lj >= LL) continue;
    int slot = lj - l0 + 3;
    float mean = stm[slot], rstd = str[slot];
    us8 v = *(const us8*)(in + ((size_t)b * LL + lj) * CC + c);
    float4 w0 = *(const float4*)&wld[j * CC + c];
    float4 w1 = *(const float4*)&wld[j * CC + c + 4];
    float wj[8] = {w0.x, w0.y, w0.z, w0.w, w1.x, w1.y, w1.z, w1.w};
#pragma unroll
    for (int u = 0; u < 8; ++u) {
      float nh = (bf2f(v[u]) - mean) * rstd;
      acc[u] += wj[u] * nh;
      ws[u] += wj[u];
    }
  }
  float4 g0 = *(const float4*)(g + c), g1 = *(const float4*)(g + c + 4);
  float4 b0 = *(const float4*)(bln + c), b1 = *(const float4*)(bln + c + 4);
  float gg[8] = {g0.x, g0.y, g0.z, g0.w, g1.x, g1.y, g1.z, g1.w};
  float bb2[8] = {b0.x, b0.y, b0.z, b0.w, b1.x, b1.y, b1.z, b1.w};
  us o[8];
#pragma unroll
  for (int u = 0; u < 8; ++u) o[u] = f2bf(gg[u] * acc[u] + bb2[u] * ws[u]);
  *(us8*)(out + ((size_t)b * LL + l) * CC + c) = *(us8*)&o[0];
}

// ---- MFMA GEMM: B-resident LDS (64KB, staged once, XOR-swizzled),
// A streamed from global/L2. K-loop is barrier-free. Tile 128x64, 4 waves 64x32.
// BIASMODE: 0=bias[col], 1=bias[row], 2=KQ combined.
template <int RELU, int F32OUT, int BIASMODE>
__global__ __launch_bounds__(256) void k_gemm(const us* __restrict__ A, long Ab,
                                              const us* __restrict__ Bm, long Bb,
                                              const float* __restrict__ bias,
                                              const float* __restrict__ bias2,
                                              void* __restrict__ outp,
                                              long orow, long obatch) {
  __shared__ __align__(16) us Bld[64 * 512];  // 64 B-rows x full K, swizzled
  int t = threadIdx.x;
  int lane = t & 63, w = t >> 6;
  int wi = w >> 1, wj = w & 1;   // wave tile: rows 64*wi, cols 32*wj
  int gx = gridDim.x, gy = gridDim.y;
  int lin = blockIdx.x + gx * (blockIdx.y + gy * blockIdx.z);
  int nwg = gx * gy * gridDim.z;
  int swz = (lin & 7) * (nwg >> 3) + (lin >> 3);
  int bx = swz % gx; int rem = swz / gx; int by = rem % gy; int bz = rem / gy;
  int i0 = by * 128, j0 = bx * 64;
  const us* Ag = A + (size_t)bz * Ab + (size_t)i0 * 512;
  const us* Bg = Bm + (size_t)bz * Bb + (size_t)j0 * 512;

  // Stage B once: wave w -> rows w*16..w*16+15. LDS dest linear; global src
  // pre-swizzled so a read with the same XOR sees the linear data (T2/m173).
  // LDS[r][X] = B[r][X ^ ((r&7)<<4 bytes)]
#pragma unroll
  for (int i = 0; i < 16; ++i) {
    int r = w * 16 + i;
    int sc = ((lane * 16) ^ ((r & 7) << 4)) >> 1;  // element offset
    gld16(Bg + (size_t)r * 512 + sc, &Bld[r * 512]);
  }
  __syncthreads();  // B resident; no further barriers

  f32x4 acc[4][2];
  const f32x4 fz = {0.f, 0.f, 0.f, 0.f};
#pragma unroll
  for (int a = 0; a < 4; ++a)
#pragma unroll
    for (int c = 0; c < 2; ++c) acc[a][c] = fz;

  const us* Aw = Ag + (size_t)(wi * 64 + (lane & 15)) * 512 + (lane >> 4) * 8;
#pragma unroll
  for (int tk = 0; tk < 8; ++tk) {
    int k0 = tk * 64;
    mbf8 af[4][2], bfr[2][2];
#pragma unroll
    for (int fi = 0; fi < 4; ++fi)
#pragma unroll
      for (int kh = 0; kh < 2; ++kh)
        af[fi][kh] = *(const mbf8*)(Aw + (size_t)(fi * 16) * 512 + k0 + kh * 32);
#pragma unroll
    for (int fj = 0; fj < 2; ++fj)
#pragma unroll
      for (int kh = 0; kh < 2; ++kh) {
        int br = wj * 32 + fj * 16 + (lane & 15);
        int cb = ((k0 + kh * 32 + (lane >> 4) * 8) * 2) ^ ((br & 7) << 4);
        bfr[fj][kh] = *(const mbf8*)((const char*)&Bld[br * 512] + cb);
      }
#pragma unroll
    for (int fi = 0; fi < 4; ++fi)
#pragma unroll
      for (int fj = 0; fj < 2; ++fj)
#pragma unroll
        for (int kh = 0; kh < 2; ++kh)
          acc[fi][fj] = __builtin_amdgcn_mfma_f32_16x16x32_bf16(af[fi][kh], bfr[fj][kh], acc[fi][fj], 0, 0, 0);
  }

#pragma unroll
  for (int fi = 0; fi < 4; ++fi)
#pragma unroll
    for (int fj = 0; fj < 2; ++fj) {
      int col = j0 + wj * 32 + fj * 16 + (lane & 15);
      float bv;
      if (BIASMODE == 2) bv = (col < CC) ? bias[col] : bias2[col - CC] * QSCALE;
      else if (BIASMODE == 0) bv = bias[col];
#pragma unroll
      for (int r = 0; r < 4; ++r) {
        int row = i0 + wi * 64 + fi * 16 + (lane >> 4) * 4 + r;
        float bvr = (BIASMODE == 1) ? bias[row] : bv;
        float v = acc[fi][fj][r] + bvr;
        if (RELU) v = fmaxf(v, 0.f);
        size_t off = (size_t)bz * obatch + (size_t)row * orow + col;
        if (F32OUT) ((float*)outp)[off] = v;
        else        ((us*)outp)[off] = f2bf(v);
      }
    }
}

// ---- flash attention, swapped-QK 32x32; mask applied via MFMA bias (R10) ----
__global__ __launch_bounds__(256) void k_attn(const us* __restrict__ KQ,
                                              const us* __restrict__ Vb,
                                              const int* __restrict__ mask,
                                              us* __restrict__ out) {
  __shared__ __align__(16) us Kld[64][72];  // [k][d]
  __shared__ __align__(16) us Vld[64][72];  // [d][k]
  __shared__ unsigned int mbits[32];
  int t = threadIdx.x;
  int lane = t & 63, w = t >> 6;
  int lo = lane & 31, hi = lane >> 5;
  int lin = blockIdx.x + 8 * (blockIdx.y + 8 * blockIdx.z);
  int swz = (lin & 7) * 128 + (lin >> 3);
  int q0 = (swz & 7) * 128;
  int h = (swz >> 3) & 7;
  int b = swz >> 6;

#pragma unroll
  for (int j = 0; j < 4; ++j) {
    int k = w * 256 + j * 64 + lane;
    unsigned long long bl = __ballot(mask[(size_t)b * LL + k] != 0);
    if (lane == 0) {
      mbits[w * 8 + j * 2]     = (unsigned int)bl;
      mbits[w * 8 + j * 2 + 1] = (unsigned int)(bl >> 32);
    }
  }

  mbf8 qf[4];
  {
    const us* qp = KQ + ((size_t)b * LL + q0 + w * 32 + lo) * 1024 + 512 + h * DH + hi * 8;
#pragma unroll
    for (int ds = 0; ds < 4; ++ds) qf[ds] = *(const mbf8*)(qp + ds * 16);
  }

  union { int i[4]; mbf8 v; } one;
  one.i[0] = 0x3F803F80; one.i[1] = 0x3F803F80; one.i[2] = 0x3F803F80; one.i[3] = 0x3F803F80;

  int sr = t >> 2, sko = (t & 3) * 16;
  const us* pkbase = KQ + ((size_t)b * LL + sr) * 1024 + h * DH + sko;
  const us* pvbase = Vb + ((size_t)b * CC + h * DH + sr) * LL + sko;
  us8 kr0 = *(const us8*)pkbase, kr1 = *(const us8*)(pkbase + 8);
  us8 vr0 = *(const us8*)pvbase, vr1 = *(const us8*)(pvbase + 8);

  const f32x16 Z16 = {0,0,0,0,0,0,0,0,0,0,0,0,0,0,0,0};
  f32x16 po0 = Z16, po1 = Z16, po2 = Z16;

  for (int kt = 0; kt < 16; ++kt) {
    asm volatile("s_waitcnt lgkmcnt(0)" ::: "memory");
    __builtin_amdgcn_s_barrier();
    asm volatile("" ::: "memory");
    *(us8*)&Kld[sr][sko]     = kr0;  *(us8*)&Kld[sr][sko + 8] = kr1;
    *(us8*)&Vld[sr][sko]     = vr0;  *(us8*)&Vld[sr][sko + 8] = vr1;
    if (kt < 15) {
      const us* pk = pkbase + (size_t)(kt + 1) * 64 * 1024;
      const us* pv = pvbase + (kt + 1) * 64;
      kr0 = *(const us8*)pk; kr1 = *(const us8*)(pk + 8);
      vr0 = *(const us8*)pv; vr1 = *(const us8*)(pv + 8);
    }
    asm volatile("s_waitcnt lgkmcnt(0)" ::: "memory");
    __builtin_amdgcn_s_barrier();
    asm volatile("" ::: "memory");

    uint2 mbp = *(const uint2*)&mbits[kt * 2];
    unsigned int b0 = (mbp.x >> lo) & 1u;
    unsigned int b1 = (mbp.y >> lo) & 1u;
    union { int i[4]; mbf8 v; } ma0, ma1;
    ma0.i[0] = (hi == 0 && !b0) ? 0xC348 : 0;  // bf16(-200) in element 0
    ma0.i[1] = 0; ma0.i[2] = 0; ma0.i[3] = 0;
    ma1.i[0] = (hi == 0 && !b1) ? 0xC348 : 0;
    ma1.i[1] = 0; ma1.i[2] = 0; ma1.i[3] = 0;
    f32x16 s0 = __builtin_amdgcn_mfma_f32_32x32x16_bf16(ma0.v, one.v, Z16, 0, 0, 0);
    f32x16 s1 = __builtin_amdgcn_mfma_f32_32x32x16_bf16(ma1.v, one.v, Z16, 0, 0, 0);
#pragma unroll
    for (int ds = 0; ds < 4; ++ds) {
      mbf8 kf0 = *(const mbf8*)&Kld[lo][ds * 16 + hi * 8];
      mbf8 kf1 = *(const mbf8*)&Kld[32 + lo][ds * 16 + hi * 8];
      s0 = __builtin_amdgcn_mfma_f32_32x32x16_bf16(kf0, qf[ds], s0, 0, 0, 0);
      s1 = __builtin_amdgcn_mfma_f32_32x32x16_bf16(kf1, qf[ds], s1, 0, 0, 0);
    }
    float p0[16], p1[16];
#pragma unroll
    for (int r = 0; r < 16; ++r) { p0[r] = fexp2(s0[r]); p1[r] = fexp2(s1[r]); }

#define PVSTEP(P, KOFF, KS)                                                          \
    {                                                                                \
      int x0, x1, y0, y1;                                                            \
      asm("v_cvt_pk_bf16_f32 %0, %1, %2" : "=v"(x0) : "v"(P[8*KS+0]), "v"(P[8*KS+1])); \
      asm("v_cvt_pk_bf16_f32 %0, %1, %2" : "=v"(x1) : "v"(P[8*KS+2]), "v"(P[8*KS+3])); \
      asm("v_cvt_pk_bf16_f32 %0, %1, %2" : "=v"(y0) : "v"(P[8*KS+4]), "v"(P[8*KS+5])); \
      asm("v_cvt_pk_bf16_f32 %0, %1, %2" : "=v"(y1) : "v"(P[8*KS+6]), "v"(P[8*KS+7])); \
      asm("v_permlane32_swap_b32 %0, %1" : "+v"(x0), "+v"(y0));                      \
      asm("v_permlane32_swap_b32 %0, %1" : "+v"(x1), "+v"(y1));                      \
      union { int i[4]; mbf8 v; } fr;                                                \
      fr.i[0] = x0; fr.i[1] = x1; fr.i[2] = y0; fr.i[3] = y1;                        \
      mbf8 vf0 = *(const mbf8*)&Vld[lo][(KOFF) + (KS) * 16 + hi * 8];                \
      mbf8 vf1 = *(const mbf8*)&Vld[32 + lo][(KOFF) + (KS) * 16 + hi * 8];           \
      po0 = __builtin_amdgcn_mfma_f32_32x32x16_bf16(fr.v, vf0, po0, 0, 0, 0);        \
      po1 = __builtin_amdgcn_mfma_f32_32x32x16_bf16(fr.v, vf1, po1, 0, 0, 0);        \
      po2 = __builtin_amdgcn_mfma_f32_32x32x16_bf16(fr.v, one.v, po2, 0, 0, 0);      \
    }
    PVSTEP(p0, 0, 0)
    PVSTEP(p0, 0, 1)
    PVSTEP(p1, 32, 0)
    PVSTEP(p1, 32, 1)
#undef PVSTEP
  }

#define WRITEO(PO, DT)                                                               \
  {                                                                                  \
    _Pragma("unroll")                                                                \
    for (int r = 0; r < 16; ++r) {                                                   \
      int qrow = (r & 3) + 8 * (r >> 2) + 4 * hi;                                    \
      float iv = 1.0f / po2[r];                                                      \
      out[((size_t)b * LL + q0 + w * 32 + qrow) * CC + h * DH + (DT) * 32 + lo]      \
          = f2bf(PO[r] * iv);                                                        \
    }                                                                                \
  }
  WRITEO(po0, 0)
  WRITEO(po1, 1)
#undef WRITEO
}

extern "C" void kernel_launch(void* const* d_in, const int* in_sizes, int n_in,
                              void* d_out, int out_size, void* d_ws, size_t ws_size,
                              hipStream_t stream) {
  const float* x        = (const float*)d_in[0];
  const int*   mask     = (const int*)d_in[1];
  const float* dw_w     = (const float*)d_in[4];
  const float* pw_w     = (const float*)d_in[5];
  const float* pw_b     = (const float*)d_in[6];
  const float* cln_g    = (const float*)d_in[7];
  const float* cln_b    = (const float*)d_in[8];
  const float* w_kv     = (const float*)d_in[9];
  const float* b_kv     = (const float*)d_in[10];
  const float* w_q      = (const float*)d_in[11];
  const float* b_q      = (const float*)d_in[12];
  const float* ln_att_g = (const float*)d_in[13];
  const float* ln_att_b = (const float*)d_in[14];
  const float* w_ffd1   = (const float*)d_in[15];
  const float* b_ffd1   = (const float*)d_in[16];
  const float* w_ffd2   = (const float*)d_in[17];
  const float* b_ffd2   = (const float*)d_in[18];
  const float* ln_ffd_g = (const float*)d_in[19];
  const float* ln_ffd_b = (const float*)d_in[20];

  // Compact layout (68.5 MB, proven): [Wb: 9*n2 bf16][A0][A1][A2][A3], KQ = A1+A2.
  const size_t n2 = (size_t)CC * CC;
  size_t actElems = (size_t)BB * LL * CC;
  us* Wb = (us*)d_ws;
  us* pw_bf = Wb;
  us* kq_bf = Wb + 4 * n2;
  us* v_bf  = Wb + 6 * n2;
  us* f1_bf = Wb + 7 * n2;
  us* f2_bf = Wb + 8 * n2;
  us* A0 = Wb + 9 * n2;
  us* A1 = A0 + actElems;
  us* A2 = A1 + actElems;
  us* A3 = A2 + actElems;
  us* KQb = A1;

  long actB = (long)LL * CC;

  k_cvtW<<<2304, 256, 0, stream>>>(pw_w, w_kv, w_q, w_ffd1, w_ffd2, Wb);
  k_in_tr<<<dim3(8, 16, BB), 256, 0, stream>>>(x, A0);

  for (int i = 0; i < 4; ++i) {
    k_lndw<<<4096, 256, 0, stream>>>(A0, cln_g + i * CC, cln_b + i * CC,
                                     dw_w + (size_t)i * CC * KW, A3);
    k_gemm<1, 0, 0><<<dim3(8, 8, BB), 256, 0, stream>>>(
        A3, actB, pw_bf + (size_t)i * n2, 0, pw_b + i * CC, pw_b + i * CC,
        A0, 512, actB);
  }

  k_ln<<<4096, 256, 0, stream>>>(A0, ln_att_g, ln_att_b, A3);
  k_gemm<0, 0, 2><<<dim3(16, 8, BB), 256, 0, stream>>>(
      A3, actB, kq_bf, 0, b_kv, b_q, KQb, 1024, (long)LL * 1024);   // K|Q (B,L,1024)
  k_gemm<0, 0, 1><<<dim3(16, 4, BB), 256, 0, stream>>>(
      v_bf, 0, A3, actB, b_kv + CC, b_kv + CC, A0, 1024, actB);     // V (B,C,L)
  k_attn<<<dim3(8, NHEAD, BB), 256, 0, stream>>>(KQb, A0, mask, A3);

  k_ln<<<4096, 256, 0, stream>>>(A3, ln_ffd_g, ln_ffd_b, A0);
  k_gemm<1, 0, 0><<<dim3(8, 8, BB), 256, 0, stream>>>(
      A0, actB, f1_bf, 0, b_ffd1, b_ffd1, A1, 512, actB);
  k_gemm<0, 1, 1><<<dim3(16, 4, BB), 256, 0, stream>>>(
      f2_bf, 0, A1, actB, b_ffd2, b_ffd2, d_out, 1024, (long)CC * LL);
}

// Round 13
// 358.638 us; speedup vs baseline: 1.4382x; 1.4382x over previous
//
#include <hip/hip_runtime.h>
#include <math.h>

#define BB 16
#define CC 512
#define LL 1024
#define NHEAD 8
#define DH 64
#define KW 7

typedef unsigned short us;
typedef unsigned short us8 __attribute__((ext_vector_type(8)));
typedef unsigned short us4 __attribute__((ext_vector_type(4)));
typedef short mbf8 __attribute__((ext_vector_type(8)));
typedef float f32x4 __attribute__((ext_vector_type(4)));
typedef float f32x16 __attribute__((ext_vector_type(16)));

#define QSCALE 0.18033688f  /* 0.125 * log2(e) */

__device__ inline us f2bf(float f) {
  union { float f; unsigned int u; } v; v.f = f;
  unsigned int u = v.u;
  u += 0x7fffu + ((u >> 16) & 1u);
  return (us)(u >> 16);
}
__device__ inline float bf2f(us s) {
  union { unsigned int u; float f; } v; v.u = ((unsigned int)s) << 16;
  return v.f;
}
__device__ __forceinline__ float fexp2(float x) {
  float r;
  asm("v_exp_f32 %0, %1" : "=v"(r) : "v"(x));
  return r;
}

// global -> LDS direct 16B copy
__device__ __forceinline__ void gld16(const void* g, void* l) {
  __builtin_amdgcn_global_load_lds(
      (__attribute__((address_space(1))) unsigned int*)(uintptr_t)(g),
      (__attribute__((address_space(3))) unsigned int*)(unsigned int)(uintptr_t)(l),
      16, 0, 0);
}

// ---- weight fp32 -> bf16 pre-convert, 9 regions of CC*CC ----
// [0..4):pw_w  [4):w_kv K-rows  [5):w_q * QSCALE  [6):w_kv V-rows  [7):ffd1 [8):ffd2
__global__ __launch_bounds__(256) void k_cvtW(const float* __restrict__ pw,
                                              const float* __restrict__ wkv,
                                              const float* __restrict__ wq,
                                              const float* __restrict__ wf1,
                                              const float* __restrict__ wf2,
                                              us* __restrict__ dst) {
  int idx = blockIdx.x * 256 + threadIdx.x;
  int e = idx * 4;
  const int n2 = CC * CC;
  int r = e / n2, o = e - r * n2;
  const float* src; float sc = 1.0f;
  if (r < 4)       { src = pw + e; }
  else if (r == 4) { src = wkv + o; }
  else if (r == 5) { src = wq + o; sc = QSCALE; }
  else if (r == 6) { src = wkv + n2 + o; }
  else if (r == 7) { src = wf1 + o; }
  else             { src = wf2 + o; }
  float4 v = *(const float4*)src;
  us4 ov; ov[0] = f2bf(v.x * sc); ov[1] = f2bf(v.y * sc);
  ov[2] = f2bf(v.z * sc); ov[3] = f2bf(v.w * sc);
  *(us4*)(dst + e) = ov;
}

// ---- x (B,C,L) f32 -> Act (B,L,C) bf16 with timing signal ----
__global__ __launch_bounds__(256) void k_in_tr(const float* __restrict__ x,
                                               us* __restrict__ act) {
  __shared__ float xt[64][69];
  int t = threadIdx.x;
  int c0 = blockIdx.x * 64;
  int l0 = blockIdx.y * 64;
  int b  = blockIdx.z;
  {
    int r = t >> 2, lo2 = (t & 3) * 16;
    const float* src = x + ((size_t)b * CC + c0 + r) * LL + l0 + lo2;
#pragma unroll
    for (int q = 0; q < 4; ++q) {
      float4 v = *(const float4*)(src + q * 4);
      xt[r][lo2 + q * 4 + 0] = v.x; xt[r][lo2 + q * 4 + 1] = v.y;
      xt[r][lo2 + q * 4 + 2] = v.z; xt[r][lo2 + q * 4 + 3] = v.w;
    }
  }
  __syncthreads();
  const float log_inc = 9.210340371976184f / 255.0f;
  int lr = t >> 2, co = (t & 3) * 16;
  int l = l0 + lr;
  us obuf[16];
#pragma unroll
  for (int u = 0; u < 16; ++u) {
    int c = c0 + co + u;
    float inv = __expf(-(float)(c & 255) * log_inc);
    float st = (float)l * inv;
    float sg = (c < 256) ? sinf(st) : cosf(st);
    obuf[u] = f2bf(xt[co + u][lr] + sg);
  }
  us* dst = act + ((size_t)b * LL + l) * CC + c0 + co;
  *(us8*)dst = *(us8*)&obuf[0];
  *(us8*)(dst + 8) = *(us8*)&obuf[8];
}

// ---- row LayerNorm over C, (B,L,C) bf16 ----
__global__ __launch_bounds__(256) void k_ln(const us* __restrict__ in,
                                            const float* __restrict__ g,
                                            const float* __restrict__ bta,
                                            us* __restrict__ out) {
  int t = threadIdx.x;
  int lane = t & 63, w = t >> 6;
  size_t row = (size_t)blockIdx.x * 4 + w;
  const us* p = in + row * CC + lane * 8;
  us8 v = *(const us8*)p;
  float f[8]; float s = 0.f, ss = 0.f;
#pragma unroll
  for (int i = 0; i < 8; ++i) { f[i] = bf2f(v[i]); s += f[i]; ss += f[i] * f[i]; }
#pragma unroll
  for (int m = 1; m < 64; m <<= 1) { s += __shfl_xor(s, m); ss += __shfl_xor(ss, m); }
  float mean = s * (1.f / CC);
  float rstd = rsqrtf(ss * (1.f / CC) - mean * mean + 1e-5f);
  float4 g0 = *(const float4*)(g + lane * 8), g1 = *(const float4*)(g + lane * 8 + 4);
  float4 b0 = *(const float4*)(bta + lane * 8), b1 = *(const float4*)(bta + lane * 8 + 4);
  float gg[8] = {g0.x, g0.y, g0.z, g0.w, g1.x, g1.y, g1.z, g1.w};
  float bb2[8] = {b0.x, b0.y, b0.z, b0.w, b1.x, b1.y, b1.z, b1.w};
  us o[8];
#pragma unroll
  for (int i = 0; i < 8; ++i) o[i] = f2bf((f[i] - mean) * rstd * gg[i] + bb2[i]);
  *(us8*)(out + row * CC + lane * 8) = *(us8*)&o[0];
}

// ---- fused LayerNorm + depthwise conv K=7 along L, (B,L,C) bf16 ----
__global__ __launch_bounds__(256) void k_lndw(const us* __restrict__ in,
                                              const float* __restrict__ g,
                                              const float* __restrict__ bln,
                                              const float* __restrict__ w,
                                              us* __restrict__ out) {
  __shared__ float wld[KW * CC];
  __shared__ float stm[12], str[12];
  int t = threadIdx.x;
  int lane = t & 63, wv = t >> 6;
  for (int i = t; i < CC * KW; i += 256) {
    int j = i >> 9, c2 = i & (CC - 1);
    wld[i] = w[c2 * KW + j];
  }
  int rowid = blockIdx.x * 4;
  int l0 = rowid & (LL - 1);
  int b = rowid >> 10;
#pragma unroll
  for (int rr = 0; rr < 3; ++rr) {
    int slot = rr * 4 + wv;
    int r = l0 - 3 + slot;
    float mean = 0.f, rstd = 0.f;
    if (r >= 0 && r < LL) {
      us8 v = *(const us8*)(in + ((size_t)b * LL + r) * CC + lane * 8);
      float s = 0.f, ss = 0.f;
#pragma unroll
      for (int i = 0; i < 8; ++i) { float f = bf2f(v[i]); s += f; ss += f * f; }
#pragma unroll
      for (int m = 1; m < 64; m <<= 1) { s += __shfl_xor(s, m); ss += __shfl_xor(ss, m); }
      mean = s * (1.f / CC);
      rstd = rsqrtf(ss * (1.f / CC) - mean * mean + 1e-5f);
    }
    if (lane == 0) { stm[slot] = mean; str[slot] = rstd; }
  }
  __syncthreads();
  int c = lane * 8;
  int l = l0 + wv;
  float acc[8] = {}, ws[8] = {};
#pragma unroll
  for (int j = 0; j < KW; ++j) {
    int lj = l + j - 3;
    if (lj < 0 || lj >= LL) continue;
    int slot = lj - l0 + 3;
    float mean = stm[slot], rstd = str[slot];
    us8 v = *(const us8*)(in + ((size_t)b * LL + lj) * CC + c);
    float4 w0 = *(const float4*)&wld[j * CC + c];
    float4 w1 = *(const float4*)&wld[j * CC + c + 4];
    float wj[8] = {w0.x, w0.y, w0.z, w0.w, w1.x, w1.y, w1.z, w1.w};
#pragma unroll
    for (int u = 0; u < 8; ++u) {
      float nh = (bf2f(v[u]) - mean) * rstd;
      acc[u] += wj[u] * nh;
      ws[u] += wj[u];
    }
  }
  float4 g0 = *(const float4*)(g + c), g1 = *(const float4*)(g + c + 4);
  float4 b0 = *(const float4*)(bln + c), b1 = *(const float4*)(bln + c + 4);
  float gg[8] = {g0.x, g0.y, g0.z, g0.w, g1.x, g1.y, g1.z, g1.w};
  float bb2[8] = {b0.x, b0.y, b0.z, b0.w, b1.x, b1.y, b1.z, b1.w};
  us o[8];
#pragma unroll
  for (int u = 0; u < 8; ++u) o[u] = f2bf(gg[u] * acc[u] + bb2[u] * ws[u]);
  *(us8*)(out + ((size_t)b * LL + l) * CC + c) = *(us8*)&o[0];
}

// ---- MFMA GEMM: 2-phase double-buffered, 64x64 tile (5 blocks/CU) ----
// 4 waves each 32x32 output. LDS 32 KB. BIASMODE: 0=bias[col], 1=bias[row],
// 2=KQ combined.
template <int RELU, int F32OUT, int BIASMODE>
__global__ __launch_bounds__(256) void k_gemm(const us* __restrict__ A, long Ab,
                                              const us* __restrict__ Bm, long Bb,
                                              const float* __restrict__ bias,
                                              const float* __restrict__ bias2,
                                              void* __restrict__ outp,
                                              long orow, long obatch) {
  __shared__ __align__(16) us Ald[2][64 * 64];
  __shared__ __align__(16) us Bld[2][64 * 64];
  int t = threadIdx.x;
  int lane = t & 63, w = t >> 6;
  int wi = w >> 1, wj = w & 1;   // wave tile: rows 32*wi, cols 32*wj
  int gx = gridDim.x, gy = gridDim.y;
  int lin = blockIdx.x + gx * (blockIdx.y + gy * blockIdx.z);
  int nwg = gx * gy * gridDim.z;
  int swz = (lin & 7) * (nwg >> 3) + (lin >> 3);
  int bx = swz % gx; int rem = swz / gx; int by = rem % gy; int bz = rem / gy;
  int i0 = by * 64, j0 = bx * 64;
  const us* Ag = A + (size_t)bz * Ab + (size_t)i0 * 512;
  const us* Bg = Bm + (size_t)bz * Bb + (size_t)j0 * 512;
  int rr = lane >> 3, cc8 = (lane & 7) * 8;
  f32x4 acc[2][2];
  const f32x4 fz = {0.f, 0.f, 0.f, 0.f};
#pragma unroll
  for (int a = 0; a < 2; ++a)
#pragma unroll
    for (int c = 0; c < 2; ++c) acc[a][c] = fz;

#define STAGE(BUF, K0)                                                        \
  {                                                                           \
    _Pragma("unroll")                                                         \
    for (int it = 0; it < 2; ++it) {                                          \
      int ch = w * 2 + it;                                                    \
      gld16(Ag + (size_t)(ch * 8 + rr) * 512 + (K0) + cc8, &Ald[BUF][ch * 512]); \
      gld16(Bg + (size_t)(ch * 8 + rr) * 512 + (K0) + cc8, &Bld[BUF][ch * 512]); \
    }                                                                         \
  }

  STAGE(0, 0)
#pragma unroll
  for (int tk = 0; tk < 8; ++tk) {
    int cur = tk & 1;
    __syncthreads();  // drains vmcnt: buffer `cur` staged; prev readers done
    if (tk < 7) STAGE(cur ^ 1, (tk + 1) * 64)  // flies under this tile's MFMAs
    mbf8 af[2][2], bfr[2][2];
#pragma unroll
    for (int fi = 0; fi < 2; ++fi)
#pragma unroll
      for (int kh = 0; kh < 2; ++kh)
        af[fi][kh] = *(const mbf8*)&Ald[cur][(wi * 32 + fi * 16 + (lane & 15)) * 64 + kh * 32 + (lane >> 4) * 8];
#pragma unroll
    for (int fj = 0; fj < 2; ++fj)
#pragma unroll
      for (int kh = 0; kh < 2; ++kh)
        bfr[fj][kh] = *(const mbf8*)&Bld[cur][(wj * 32 + fj * 16 + (lane & 15)) * 64 + kh * 32 + (lane >> 4) * 8];
#pragma unroll
    for (int fi = 0; fi < 2; ++fi)
#pragma unroll
      for (int fj = 0; fj < 2; ++fj)
#pragma unroll
        for (int kh = 0; kh < 2; ++kh)
          acc[fi][fj] = __builtin_amdgcn_mfma_f32_16x16x32_bf16(af[fi][kh], bfr[fj][kh], acc[fi][fj], 0, 0, 0);
  }
#undef STAGE

#pragma unroll
  for (int fi = 0; fi < 2; ++fi)
#pragma unroll
    for (int fj = 0; fj < 2; ++fj) {
      int col = j0 + wj * 32 + fj * 16 + (lane & 15);
      float bv;
      if (BIASMODE == 2) bv = (col < CC) ? bias[col] : bias2[col - CC] * QSCALE;
      else if (BIASMODE == 0) bv = bias[col];
#pragma unroll
      for (int r = 0; r < 4; ++r) {
        int row = i0 + wi * 32 + fi * 16 + (lane >> 4) * 4 + r;
        float bvr = (BIASMODE == 1) ? bias[row] : bv;
        float v = acc[fi][fj][r] + bvr;
        if (RELU) v = fmaxf(v, 0.f);
        size_t off = (size_t)bz * obatch + (size_t)row * orow + col;
        if (F32OUT) ((float*)outp)[off] = v;
        else        ((us*)outp)[off] = f2bf(v);
      }
    }
}

// ---- flash attention, swapped-QK 32x32; mask applied via MFMA bias (R10) ----
__global__ __launch_bounds__(256) void k_attn(const us* __restrict__ KQ,
                                              const us* __restrict__ Vb,
                                              const int* __restrict__ mask,
                                              us* __restrict__ out) {
  __shared__ __align__(16) us Kld[64][72];  // [k][d]
  __shared__ __align__(16) us Vld[64][72];  // [d][k]
  __shared__ unsigned int mbits[32];
  int t = threadIdx.x;
  int lane = t & 63, w = t >> 6;
  int lo = lane & 31, hi = lane >> 5;
  int lin = blockIdx.x + 8 * (blockIdx.y + 8 * blockIdx.z);
  int swz = (lin & 7) * 128 + (lin >> 3);
  int q0 = (swz & 7) * 128;
  int h = (swz >> 3) & 7;
  int b = swz >> 6;

#pragma unroll
  for (int j = 0; j < 4; ++j) {
    int k = w * 256 + j * 64 + lane;
    unsigned long long bl = __ballot(mask[(size_t)b * LL + k] != 0);
    if (lane == 0) {
      mbits[w * 8 + j * 2]     = (unsigned int)bl;
      mbits[w * 8 + j * 2 + 1] = (unsigned int)(bl >> 32);
    }
  }

  mbf8 qf[4];
  {
    const us* qp = KQ + ((size_t)b * LL + q0 + w * 32 + lo) * 1024 + 512 + h * DH + hi * 8;
#pragma unroll
    for (int ds = 0; ds < 4; ++ds) qf[ds] = *(const mbf8*)(qp + ds * 16);
  }

  union { int i[4]; mbf8 v; } one;
  one.i[0] = 0x3F803F80; one.i[1] = 0x3F803F80; one.i[2] = 0x3F803F80; one.i[3] = 0x3F803F80;

  int sr = t >> 2, sko = (t & 3) * 16;
  const us* pkbase = KQ + ((size_t)b * LL + sr) * 1024 + h * DH + sko;
  const us* pvbase = Vb + ((size_t)b * CC + h * DH + sr) * LL + sko;
  us8 kr0 = *(const us8*)pkbase, kr1 = *(const us8*)(pkbase + 8);
  us8 vr0 = *(const us8*)pvbase, vr1 = *(const us8*)(pvbase + 8);

  const f32x16 Z16 = {0,0,0,0,0,0,0,0,0,0,0,0,0,0,0,0};
  f32x16 po0 = Z16, po1 = Z16, po2 = Z16;

  for (int kt = 0; kt < 16; ++kt) {
    asm volatile("s_waitcnt lgkmcnt(0)" ::: "memory");
    __builtin_amdgcn_s_barrier();
    asm volatile("" ::: "memory");
    *(us8*)&Kld[sr][sko]     = kr0;  *(us8*)&Kld[sr][sko + 8] = kr1;
    *(us8*)&Vld[sr][sko]     = vr0;  *(us8*)&Vld[sr][sko + 8] = vr1;
    if (kt < 15) {
      const us* pk = pkbase + (size_t)(kt + 1) * 64 * 1024;
      const us* pv = pvbase + (kt + 1) * 64;
      kr0 = *(const us8*)pk; kr1 = *(const us8*)(pk + 8);
      vr0 = *(const us8*)pv; vr1 = *(const us8*)(pv + 8);
    }
    asm volatile("s_waitcnt lgkmcnt(0)" ::: "memory");
    __builtin_amdgcn_s_barrier();
    asm volatile("" ::: "memory");

    uint2 mbp = *(const uint2*)&mbits[kt * 2];
    unsigned int b0 = (mbp.x >> lo) & 1u;
    unsigned int b1 = (mbp.y >> lo) & 1u;
    union { int i[4]; mbf8 v; } ma0, ma1;
    ma0.i[0] = (hi == 0 && !b0) ? 0xC348 : 0;  // bf16(-200) in element 0
    ma0.i[1] = 0; ma0.i[2] = 0; ma0.i[3] = 0;
    ma1.i[0] = (hi == 0 && !b1) ? 0xC348 : 0;
    ma1.i[1] = 0; ma1.i[2] = 0; ma1.i[3] = 0;
    f32x16 s0 = __builtin_amdgcn_mfma_f32_32x32x16_bf16(ma0.v, one.v, Z16, 0, 0, 0);
    f32x16 s1 = __builtin_amdgcn_mfma_f32_32x32x16_bf16(ma1.v, one.v, Z16, 0, 0, 0);
#pragma unroll
    for (int ds = 0; ds < 4; ++ds) {
      mbf8 kf0 = *(const mbf8*)&Kld[lo][ds * 16 + hi * 8];
      mbf8 kf1 = *(const mbf8*)&Kld[32 + lo][ds * 16 + hi * 8];
      s0 = __builtin_amdgcn_mfma_f32_32x32x16_bf16(kf0, qf[ds], s0, 0, 0, 0);
      s1 = __builtin_amdgcn_mfma_f32_32x32x16_bf16(kf1, qf[ds], s1, 0, 0, 0);
    }
    float p0[16], p1[16];
#pragma unroll
    for (int r = 0; r < 16; ++r) { p0[r] = fexp2(s0[r]); p1[r] = fexp2(s1[r]); }

#define PVSTEP(P, KOFF, KS)                                                          \
    {                                                                                \
      int x0, x1, y0, y1;                                                            \
      asm("v_cvt_pk_bf16_f32 %0, %1, %2" : "=v"(x0) : "v"(P[8*KS+0]), "v"(P[8*KS+1])); \
      asm("v_cvt_pk_bf16_f32 %0, %1, %2" : "=v"(x1) : "v"(P[8*KS+2]), "v"(P[8*KS+3])); \
      asm("v_cvt_pk_bf16_f32 %0, %1, %2" : "=v"(y0) : "v"(P[8*KS+4]), "v"(P[8*KS+5])); \
      asm("v_cvt_pk_bf16_f32 %0, %1, %2" : "=v"(y1) : "v"(P[8*KS+6]), "v"(P[8*KS+7])); \
      asm("v_permlane32_swap_b32 %0, %1" : "+v"(x0), "+v"(y0));                      \
      asm("v_permlane32_swap_b32 %0, %1" : "+v"(x1), "+v"(y1));                      \
      union { int i[4]; mbf8 v; } fr;                                                \
      fr.i[0] = x0; fr.i[1] = x1; fr.i[2] = y0; fr.i[3] = y1;                        \
      mbf8 vf0 = *(const mbf8*)&Vld[lo][(KOFF) + (KS) * 16 + hi * 8];                \
      mbf8 vf1 = *(const mbf8*)&Vld[32 + lo][(KOFF) + (KS) * 16 + hi * 8];           \
      po0 = __builtin_amdgcn_mfma_f32_32x32x16_bf16(fr.v, vf0, po0, 0, 0, 0);        \
      po1 = __builtin_amdgcn_mfma_f32_32x32x16_bf16(fr.v, vf1, po1, 0, 0, 0);        \
      po2 = __builtin_amdgcn_mfma_f32_32x32x16_bf16(fr.v, one.v, po2, 0, 0, 0);      \
    }
    PVSTEP(p0, 0, 0)
    PVSTEP(p0, 0, 1)
    PVSTEP(p1, 32, 0)
    PVSTEP(p1, 32, 1)
#undef PVSTEP
  }

#define WRITEO(PO, DT)                                                               \
  {                                                                                  \
    _Pragma("unroll")                                                                \
    for (int r = 0; r < 16; ++r) {                                                   \
      int qrow = (r & 3) + 8 * (r >> 2) + 4 * hi;                                    \
      float iv = 1.0f / po2[r];                                                      \
      out[((size_t)b * LL + q0 + w * 32 + qrow) * CC + h * DH + (DT) * 32 + lo]      \
          = f2bf(PO[r] * iv);                                                        \
    }                                                                                \
  }
  WRITEO(po0, 0)
  WRITEO(po1, 1)
#undef WRITEO
}

extern "C" void kernel_launch(void* const* d_in, const int* in_sizes, int n_in,
                              void* d_out, int out_size, void* d_ws, size_t ws_size,
                              hipStream_t stream) {
  const float* x        = (const float*)d_in[0];
  const int*   mask     = (const int*)d_in[1];
  const float* dw_w     = (const float*)d_in[4];
  const float* pw_w     = (const float*)d_in[5];
  const float* pw_b     = (const float*)d_in[6];
  const float* cln_g    = (const float*)d_in[7];
  const float* cln_b    = (const float*)d_in[8];
  const float* w_kv     = (const float*)d_in[9];
  const float* b_kv     = (const float*)d_in[10];
  const float* w_q      = (const float*)d_in[11];
  const float* b_q      = (const float*)d_in[12];
  const float* ln_att_g = (const float*)d_in[13];
  const float* ln_att_b = (const float*)d_in[14];
  const float* w_ffd1   = (const float*)d_in[15];
  const float* b_ffd1   = (const float*)d_in[16];
  const float* w_ffd2   = (const float*)d_in[17];
  const float* b_ffd2   = (const float*)d_in[18];
  const float* ln_ffd_g = (const float*)d_in[19];
  const float* ln_ffd_b = (const float*)d_in[20];

  // Compact layout (68.5 MB, proven): [Wb: 9*n2 bf16][A0][A1][A2][A3], KQ = A1+A2.
  const size_t n2 = (size_t)CC * CC;
  size_t actElems = (size_t)BB * LL * CC;
  us* Wb = (us*)d_ws;
  us* pw_bf = Wb;
  us* kq_bf = Wb + 4 * n2;
  us* v_bf  = Wb + 6 * n2;
  us* f1_bf = Wb + 7 * n2;
  us* f2_bf = Wb + 8 * n2;
  us* A0 = Wb + 9 * n2;
  us* A1 = A0 + actElems;
  us* A2 = A1 + actElems;
  us* A3 = A2 + actElems;
  us* KQb = A1;

  long actB = (long)LL * CC;

  k_cvtW<<<2304, 256, 0, stream>>>(pw_w, w_kv, w_q, w_ffd1, w_ffd2, Wb);
  k_in_tr<<<dim3(8, 16, BB), 256, 0, stream>>>(x, A0);

  for (int i = 0; i < 4; ++i) {
    k_lndw<<<4096, 256, 0, stream>>>(A0, cln_g + i * CC, cln_b + i * CC,
                                     dw_w + (size_t)i * CC * KW, A3);
    k_gemm<1, 0, 0><<<dim3(8, 16, BB), 256, 0, stream>>>(
        A3, actB, pw_bf + (size_t)i * n2, 0, pw_b + i * CC, pw_b + i * CC,
        A0, 512, actB);
  }

  k_ln<<<4096, 256, 0, stream>>>(A0, ln_att_g, ln_att_b, A3);
  k_gemm<0, 0, 2><<<dim3(16, 16, BB), 256, 0, stream>>>(
      A3, actB, kq_bf, 0, b_kv, b_q, KQb, 1024, (long)LL * 1024);   // K|Q (B,L,1024)
  k_gemm<0, 0, 1><<<dim3(16, 8, BB), 256, 0, stream>>>(
      v_bf, 0, A3, actB, b_kv + CC, b_kv + CC, A0, 1024, actB);     // V (B,C,L)
  k_attn<<<dim3(8, NHEAD, BB), 256, 0, stream>>>(KQb, A0, mask, A3);

  k_ln<<<4096, 256, 0, stream>>>(A3, ln_ffd_g, ln_ffd_b, A0);
  k_gemm<1, 0, 0><<<dim3(8, 16, BB), 256, 0, stream>>>(
      A0, actB, f1_bf, 0, b_ffd1, b_ffd1, A1, 512, actB);
  k_gemm<0, 1, 1><<<dim3(16, 8, BB), 256, 0, stream>>>(
      f2_bf, 0, A1, actB, b_ffd2, b_ffd2, d_out, 1024, (long)CC * LL);
}

// Round 15
// 347.529 us; speedup vs baseline: 1.4842x; 1.0320x over previous
//
#include <hip/hip_runtime.h>
#include <math.h>

#define BB 16
#define CC 512
#define LL 1024
#define NHEAD 8
#define DH 64
#define KW 7

typedef unsigned short us;
typedef unsigned short us8 __attribute__((ext_vector_type(8)));
typedef unsigned short us4 __attribute__((ext_vector_type(4)));
typedef short mbf8 __attribute__((ext_vector_type(8)));
typedef float f32x4 __attribute__((ext_vector_type(4)));
typedef float f32x16 __attribute__((ext_vector_type(16)));

#define QSCALE 0.18033688f  /* 0.125 * log2(e) */

__device__ inline us f2bf(float f) {
  union { float f; unsigned int u; } v; v.f = f;
  unsigned int u = v.u;
  u += 0x7fffu + ((u >> 16) & 1u);
  return (us)(u >> 16);
}
__device__ inline float bf2f(us s) {
  union { unsigned int u; float f; } v; v.u = ((unsigned int)s) << 16;
  return v.f;
}
__device__ __forceinline__ float fexp2(float x) {
  float r;
  asm("v_exp_f32 %0, %1" : "=v"(r) : "v"(x));
  return r;
}

// global -> LDS direct 16B copy
__device__ __forceinline__ void gld16(const void* g, void* l) {
  __builtin_amdgcn_global_load_lds(
      (__attribute__((address_space(1))) unsigned int*)(uintptr_t)(g),
      (__attribute__((address_space(3))) unsigned int*)(unsigned int)(uintptr_t)(l),
      16, 0, 0);
}

// ---- weight fp32 -> bf16 pre-convert, 9 regions of CC*CC ----
// [0..4):pw_w  [4):w_kv K-rows  [5):w_q * QSCALE  [6):w_kv V-rows  [7):ffd1 [8):ffd2
__global__ __launch_bounds__(256) void k_cvtW(const float* __restrict__ pw,
                                              const float* __restrict__ wkv,
                                              const float* __restrict__ wq,
                                              const float* __restrict__ wf1,
                                              const float* __restrict__ wf2,
                                              us* __restrict__ dst) {
  int idx = blockIdx.x * 256 + threadIdx.x;
  int e = idx * 4;
  const int n2 = CC * CC;
  int r = e / n2, o = e - r * n2;
  const float* src; float sc = 1.0f;
  if (r < 4)       { src = pw + e; }
  else if (r == 4) { src = wkv + o; }
  else if (r == 5) { src = wq + o; sc = QSCALE; }
  else if (r == 6) { src = wkv + n2 + o; }
  else if (r == 7) { src = wf1 + o; }
  else             { src = wf2 + o; }
  float4 v = *(const float4*)src;
  us4 ov; ov[0] = f2bf(v.x * sc); ov[1] = f2bf(v.y * sc);
  ov[2] = f2bf(v.z * sc); ov[3] = f2bf(v.w * sc);
  *(us4*)(dst + e) = ov;
}

// ---- x (B,C,L) f32 -> Act (B,L,C) bf16 with timing signal ----
__global__ __launch_bounds__(256) void k_in_tr(const float* __restrict__ x,
                                               us* __restrict__ act) {
  __shared__ float xt[64][69];
  int t = threadIdx.x;
  int c0 = blockIdx.x * 64;
  int l0 = blockIdx.y * 64;
  int b  = blockIdx.z;
  {
    int r = t >> 2, lo2 = (t & 3) * 16;
    const float* src = x + ((size_t)b * CC + c0 + r) * LL + l0 + lo2;
#pragma unroll
    for (int q = 0; q < 4; ++q) {
      float4 v = *(const float4*)(src + q * 4);
      xt[r][lo2 + q * 4 + 0] = v.x; xt[r][lo2 + q * 4 + 1] = v.y;
      xt[r][lo2 + q * 4 + 2] = v.z; xt[r][lo2 + q * 4 + 3] = v.w;
    }
  }
  __syncthreads();
  const float log_inc = 9.210340371976184f / 255.0f;
  int lr = t >> 2, co = (t & 3) * 16;
  int l = l0 + lr;
  us obuf[16];
#pragma unroll
  for (int u = 0; u < 16; ++u) {
    int c = c0 + co + u;
    float inv = __expf(-(float)(c & 255) * log_inc);
    float st = (float)l * inv;
    float sg = (c < 256) ? sinf(st) : cosf(st);
    obuf[u] = f2bf(xt[co + u][lr] + sg);
  }
  us* dst = act + ((size_t)b * LL + l) * CC + c0 + co;
  *(us8*)dst = *(us8*)&obuf[0];
  *(us8*)(dst + 8) = *(us8*)&obuf[8];
}

// ---- row LayerNorm over C, (B,L,C) bf16 ----
__global__ __launch_bounds__(256) void k_ln(const us* __restrict__ in,
                                            const float* __restrict__ g,
                                            const float* __restrict__ bta,
                                            us* __restrict__ out) {
  int t = threadIdx.x;
  int lane = t & 63, w = t >> 6;
  size_t row = (size_t)blockIdx.x * 4 + w;
  const us* p = in + row * CC + lane * 8;
  us8 v = *(const us8*)p;
  float f[8]; float s = 0.f, ss = 0.f;
#pragma unroll
  for (int i = 0; i < 8; ++i) { f[i] = bf2f(v[i]); s += f[i]; ss += f[i] * f[i]; }
#pragma unroll
  for (int m = 1; m < 64; m <<= 1) { s += __shfl_xor(s, m); ss += __shfl_xor(ss, m); }
  float mean = s * (1.f / CC);
  float rstd = rsqrtf(ss * (1.f / CC) - mean * mean + 1e-5f);
  float4 g0 = *(const float4*)(g + lane * 8), g1 = *(const float4*)(g + lane * 8 + 4);
  float4 b0 = *(const float4*)(bta + lane * 8), b1 = *(const float4*)(bta + lane * 8 + 4);
  float gg[8] = {g0.x, g0.y, g0.z, g0.w, g1.x, g1.y, g1.z, g1.w};
  float bb2[8] = {b0.x, b0.y, b0.z, b0.w, b1.x, b1.y, b1.z, b1.w};
  us o[8];
#pragma unroll
  for (int i = 0; i < 8; ++i) o[i] = f2bf((f[i] - mean) * rstd * gg[i] + bb2[i]);
  *(us8*)(out + row * CC + lane * 8) = *(us8*)&o[0];
}

// ---- fused LayerNorm + depthwise conv K=7 along L, (B,L,C) bf16 ----
__global__ __launch_bounds__(256) void k_lndw(const us* __restrict__ in,
                                              const float* __restrict__ g,
                                              const float* __restrict__ bln,
                                              const float* __restrict__ w,
                                              us* __restrict__ out) {
  __shared__ float wld[KW * CC];
  __shared__ float stm[12], str[12];
  int t = threadIdx.x;
  int lane = t & 63, wv = t >> 6;
  for (int i = t; i < CC * KW; i += 256) {
    int j = i >> 9, c2 = i & (CC - 1);
    wld[i] = w[c2 * KW + j];
  }
  int rowid = blockIdx.x * 4;
  int l0 = rowid & (LL - 1);
  int b = rowid >> 10;
#pragma unroll
  for (int rr = 0; rr < 3; ++rr) {
    int slot = rr * 4 + wv;
    int r = l0 - 3 + slot;
    float mean = 0.f, rstd = 0.f;
    if (r >= 0 && r < LL) {
      us8 v = *(const us8*)(in + ((size_t)b * LL + r) * CC + lane * 8);
      float s = 0.f, ss = 0.f;
#pragma unroll
      for (int i = 0; i < 8; ++i) { float f = bf2f(v[i]); s += f; ss += f * f; }
#pragma unroll
      for (int m = 1; m < 64; m <<= 1) { s += __shfl_xor(s, m); ss += __shfl_xor(ss, m); }
      mean = s * (1.f / CC);
      rstd = rsqrtf(ss * (1.f / CC) - mean * mean + 1e-5f);
    }
    if (lane == 0) { stm[slot] = mean; str[slot] = rstd; }
  }
  __syncthreads();
  int c = lane * 8;
  int l = l0 + wv;
  float acc[8] = {}, ws[8] = {};
#pragma unroll
  for (int j = 0; j < KW; ++j) {
    int lj = l + j - 3;
    if (lj < 0 || lj >= LL) continue;
    int slot = lj - l0 + 3;
    float mean = stm[slot], rstd = str[slot];
    us8 v = *(const us8*)(in + ((size_t)b * LL + lj) * CC + c);
    float4 w0 = *(const float4*)&wld[j * CC + c];
    float4 w1 = *(const float4*)&wld[j * CC + c + 4];
    float wj[8] = {w0.x, w0.y, w0.z, w0.w, w1.x, w1.y, w1.z, w1.w};
#pragma unroll
    for (int u = 0; u < 8; ++u) {
      float nh = (bf2f(v[u]) - mean) * rstd;
      acc[u] += wj[u] * nh;
      ws[u] += wj[u];
    }
  }
  float4 g0 = *(const float4*)(g + c), g1 = *(const float4*)(g + c + 4);
  float4 b0 = *(const float4*)(bln + c), b1 = *(const float4*)(bln + c + 4);
  float gg[8] = {g0.x, g0.y, g0.z, g0.w, g1.x, g1.y, g1.z, g1.w};
  float bb2[8] = {b0.x, b0.y, b0.z, b0.w, b1.x, b1.y, b1.z, b1.w};
  us o[8];
#pragma unroll
  for (int u = 0; u < 8; ++u) o[u] = f2bf(gg[u] * acc[u] + bb2[u] * ws[u]);
  *(us8*)(out + ((size_t)b * LL + l) * CC + c) = *(us8*)&o[0];
}

// ---- MFMA GEMM: 2-phase double-buffered, 128x64 tile (R11-proven) ----
// 4 waves each 64x32. LDS 48 KB. BIASMODE: 0=bias[col], 1=bias[row], 2=KQ.
template <int RELU, int F32OUT, int BIASMODE>
__global__ __launch_bounds__(256) void k_gemm(const us* __restrict__ A, long Ab,
                                              const us* __restrict__ Bm, long Bb,
                                              const float* __restrict__ bias,
                                              const float* __restrict__ bias2,
                                              void* __restrict__ outp,
                                              long orow, long obatch) {
  __shared__ __align__(16) us Ald[2][128 * 64];
  __shared__ __align__(16) us Bld[2][64 * 64];
  int t = threadIdx.x;
  int lane = t & 63, w = t >> 6;
  int wi = w >> 1, wj = w & 1;   // wave tile: rows 64*wi, cols 32*wj
  int gx = gridDim.x, gy = gridDim.y;
  int lin = blockIdx.x + gx * (blockIdx.y + gy * blockIdx.z);
  int nwg = gx * gy * gridDim.z;
  int swz = (lin & 7) * (nwg >> 3) + (lin >> 3);
  int bx = swz % gx; int rem = swz / gx; int by = rem % gy; int bz = rem / gy;
  int i0 = by * 128, j0 = bx * 64;
  const us* Ag = A + (size_t)bz * Ab + (size_t)i0 * 512;
  const us* Bg = Bm + (size_t)bz * Bb + (size_t)j0 * 512;
  int rr = lane >> 3, cc8 = (lane & 7) * 8;
  f32x4 acc[4][2];
  const f32x4 fz = {0.f, 0.f, 0.f, 0.f};
#pragma unroll
  for (int a = 0; a < 4; ++a)
#pragma unroll
    for (int c = 0; c < 2; ++c) acc[a][c] = fz;

#define STAGE(BUF, K0)                                                        \
  {                                                                           \
    _Pragma("unroll")                                                         \
    for (int it = 0; it < 4; ++it) {                                          \
      int ch = w * 4 + it;                                                    \
      gld16(Ag + (size_t)(ch * 8 + rr) * 512 + (K0) + cc8, &Ald[BUF][ch * 512]); \
    }                                                                         \
    _Pragma("unroll")                                                         \
    for (int it = 0; it < 2; ++it) {                                          \
      int ch = w * 2 + it;                                                    \
      gld16(Bg + (size_t)(ch * 8 + rr) * 512 + (K0) + cc8, &Bld[BUF][ch * 512]); \
    }                                                                         \
  }

  STAGE(0, 0)
#pragma unroll
  for (int tk = 0; tk < 8; ++tk) {
    int cur = tk & 1;
    __syncthreads();  // drains vmcnt: buffer `cur` staged; prev readers done
    if (tk < 7) STAGE(cur ^ 1, (tk + 1) * 64)  // flies under this tile's MFMAs
    mbf8 af[4][2], bfr[2][2];
#pragma unroll
    for (int fi = 0; fi < 4; ++fi)
#pragma unroll
      for (int kh = 0; kh < 2; ++kh)
        af[fi][kh] = *(const mbf8*)&Ald[cur][(wi * 64 + fi * 16 + (lane & 15)) * 64 + kh * 32 + (lane >> 4) * 8];
#pragma unroll
    for (int fj = 0; fj < 2; ++fj)
#pragma unroll
      for (int kh = 0; kh < 2; ++kh)
        bfr[fj][kh] = *(const mbf8*)&Bld[cur][(wj * 32 + fj * 16 + (lane & 15)) * 64 + kh * 32 + (lane >> 4) * 8];
#pragma unroll
    for (int fi = 0; fi < 4; ++fi)
#pragma unroll
      for (int fj = 0; fj < 2; ++fj)
#pragma unroll
        for (int kh = 0; kh < 2; ++kh)
          acc[fi][fj] = __builtin_amdgcn_mfma_f32_16x16x32_bf16(af[fi][kh], bfr[fj][kh], acc[fi][fj], 0, 0, 0);
  }
#undef STAGE

#pragma unroll
  for (int fi = 0; fi < 4; ++fi)
#pragma unroll
    for (int fj = 0; fj < 2; ++fj) {
      int col = j0 + wj * 32 + fj * 16 + (lane & 15);
      float bv;
      if (BIASMODE == 2) bv = (col < CC) ? bias[col] : bias2[col - CC] * QSCALE;
      else if (BIASMODE == 0) bv = bias[col];
#pragma unroll
      for (int r = 0; r < 4; ++r) {
        int row = i0 + wi * 64 + fi * 16 + (lane >> 4) * 4 + r;
        float bvr = (BIASMODE == 1) ? bias[row] : bv;
        float v = acc[fi][fj][r] + bvr;
        if (RELU) v = fmaxf(v, 0.f);
        size_t off = (size_t)bz * obatch + (size_t)row * orow + col;
        if (F32OUT) ((float*)outp)[off] = v;
        else        ((us*)outp)[off] = f2bf(v);
      }
    }
}

// ---- flash attention, swapped-QK 32x32; 64 q rows per wave (2 sets A/B) ----
// K/V LDS fragments reused across both sets: halved LDS reads + barriers per q.
// grid (L/256, NHEAD, B), 256 thr = 4 waves.
__global__ __launch_bounds__(256) void k_attn(const us* __restrict__ KQ,
                                              const us* __restrict__ Vb,
                                              const int* __restrict__ mask,
                                              us* __restrict__ out) {
  __shared__ __align__(16) us Kld[64][72];  // [k][d]
  __shared__ __align__(16) us Vld[64][72];  // [d][k]
  __shared__ unsigned int mbits[32];
  int t = threadIdx.x;
  int lane = t & 63, w = t >> 6;
  int lo = lane & 31, hi = lane >> 5;
  // XCD swizzle over 512 blocks
  int lin = blockIdx.x + 4 * (blockIdx.y + 8 * blockIdx.z);
  int swz = (lin & 7) * 64 + (lin >> 3);
  int q0 = (swz & 3) * 256;
  int h = (swz >> 2) & 7;
  int b = swz >> 5;

#pragma unroll
  for (int j = 0; j < 4; ++j) {
    int k = w * 256 + j * 64 + lane;
    unsigned long long bl = __ballot(mask[(size_t)b * LL + k] != 0);
    if (lane == 0) {
      mbits[w * 8 + j * 2]     = (unsigned int)bl;
      mbits[w * 8 + j * 2 + 1] = (unsigned int)(bl >> 32);
    }
  }

  mbf8 qfA[4], qfB[4];
  {
    const us* qpA = KQ + ((size_t)b * LL + q0 + w * 64 + lo) * 1024 + 512 + h * DH + hi * 8;
    const us* qpB = qpA + (size_t)32 * 1024;
#pragma unroll
    for (int ds = 0; ds < 4; ++ds) {
      qfA[ds] = *(const mbf8*)(qpA + ds * 16);
      qfB[ds] = *(const mbf8*)(qpB + ds * 16);
    }
  }

  union { int i[4]; mbf8 v; } one;
  one.i[0] = 0x3F803F80; one.i[1] = 0x3F803F80; one.i[2] = 0x3F803F80; one.i[3] = 0x3F803F80;

  int sr = t >> 2, sko = (t & 3) * 16;
  const us* pkbase = KQ + ((size_t)b * LL + sr) * 1024 + h * DH + sko;
  const us* pvbase = Vb + ((size_t)b * CC + h * DH + sr) * LL + sko;
  us8 kr0 = *(const us8*)pkbase, kr1 = *(const us8*)(pkbase + 8);
  us8 vr0 = *(const us8*)pvbase, vr1 = *(const us8*)(pvbase + 8);

  const f32x16 Z16 = {0,0,0,0,0,0,0,0,0,0,0,0,0,0,0,0};
  f32x16 poA0 = Z16, poA1 = Z16, poB0 = Z16, poB1 = Z16, po2A = Z16, po2B = Z16;

  for (int kt = 0; kt < 16; ++kt) {
    asm volatile("s_waitcnt lgkmcnt(0)" ::: "memory");
    __builtin_amdgcn_s_barrier();
    asm volatile("" ::: "memory");
    *(us8*)&Kld[sr][sko]     = kr0;  *(us8*)&Kld[sr][sko + 8] = kr1;
    *(us8*)&Vld[sr][sko]     = vr0;  *(us8*)&Vld[sr][sko + 8] = vr1;
    if (kt < 15) {
      const us* pk = pkbase + (size_t)(kt + 1) * 64 * 1024;
      const us* pv = pvbase + (kt + 1) * 64;
      kr0 = *(const us8*)pk; kr1 = *(const us8*)(pk + 8);
      vr0 = *(const us8*)pv; vr1 = *(const us8*)(pv + 8);
    }
    asm volatile("s_waitcnt lgkmcnt(0)" ::: "memory");
    __builtin_amdgcn_s_barrier();
    asm volatile("" ::: "memory");

    // mask bias (k-only, shared by both q-sets)
    uint2 mbp = *(const uint2*)&mbits[kt * 2];
    unsigned int b0 = (mbp.x >> lo) & 1u;
    unsigned int b1 = (mbp.y >> lo) & 1u;
    union { int i[4]; mbf8 v; } ma0, ma1;
    ma0.i[0] = (hi == 0 && !b0) ? 0xC348 : 0;  // bf16(-200) in element 0
    ma0.i[1] = 0; ma0.i[2] = 0; ma0.i[3] = 0;
    ma1.i[0] = (hi == 0 && !b1) ? 0xC348 : 0;
    ma1.i[1] = 0; ma1.i[2] = 0; ma1.i[3] = 0;
    f32x16 sA0 = __builtin_amdgcn_mfma_f32_32x32x16_bf16(ma0.v, one.v, Z16, 0, 0, 0);
    f32x16 sA1 = __builtin_amdgcn_mfma_f32_32x32x16_bf16(ma1.v, one.v, Z16, 0, 0, 0);
    f32x16 sB0 = sA0, sB1 = sA1;
#pragma unroll
    for (int ds = 0; ds < 4; ++ds) {
      mbf8 kf0 = *(const mbf8*)&Kld[lo][ds * 16 + hi * 8];
      mbf8 kf1 = *(const mbf8*)&Kld[32 + lo][ds * 16 + hi * 8];
      sA0 = __builtin_amdgcn_mfma_f32_32x32x16_bf16(kf0, qfA[ds], sA0, 0, 0, 0);
      sA1 = __builtin_amdgcn_mfma_f32_32x32x16_bf16(kf1, qfA[ds], sA1, 0, 0, 0);
      sB0 = __builtin_amdgcn_mfma_f32_32x32x16_bf16(kf0, qfB[ds], sB0, 0, 0, 0);
      sB1 = __builtin_amdgcn_mfma_f32_32x32x16_bf16(kf1, qfB[ds], sB1, 0, 0, 0);
    }
    float pA0[16], pA1[16], pB0[16], pB1[16];
#pragma unroll
    for (int r = 0; r < 16; ++r) {
      pA0[r] = fexp2(sA0[r]); pA1[r] = fexp2(sA1[r]);
      pB0[r] = fexp2(sB0[r]); pB1[r] = fexp2(sB1[r]);
    }

    // per V-slice: load vf once, feed both sets' PV + rowsum
#define CVT(P, KS, FR)                                                               \
    {                                                                                \
      int x0, x1, y0, y1;                                                            \
      asm("v_cvt_pk_bf16_f32 %0, %1, %2" : "=v"(x0) : "v"(P[8*KS+0]), "v"(P[8*KS+1])); \
      asm("v_cvt_pk_bf16_f32 %0, %1, %2" : "=v"(x1) : "v"(P[8*KS+2]), "v"(P[8*KS+3])); \
      asm("v_cvt_pk_bf16_f32 %0, %1, %2" : "=v"(y0) : "v"(P[8*KS+4]), "v"(P[8*KS+5])); \
      asm("v_cvt_pk_bf16_f32 %0, %1, %2" : "=v"(y1) : "v"(P[8*KS+6]), "v"(P[8*KS+7])); \
      asm("v_permlane32_swap_b32 %0, %1" : "+v"(x0), "+v"(y0));                      \
      asm("v_permlane32_swap_b32 %0, %1" : "+v"(x1), "+v"(y1));                      \
      FR.i[0] = x0; FR.i[1] = x1; FR.i[2] = y0; FR.i[3] = y1;                        \
    }
#define PVSTEP(PA, PB, KOFF, KS)                                                     \
    {                                                                                \
      union { int i[4]; mbf8 v; } frA, frB;                                          \
      CVT(PA, KS, frA)                                                               \
      CVT(PB, KS, frB)                                                               \
      mbf8 vf0 = *(const mbf8*)&Vld[lo][(KOFF) + (KS) * 16 + hi * 8];                \
      mbf8 vf1 = *(const mbf8*)&Vld[32 + lo][(KOFF) + (KS) * 16 + hi * 8];           \
      poA0 = __builtin_amdgcn_mfma_f32_32x32x16_bf16(frA.v, vf0, poA0, 0, 0, 0);     \
      poA1 = __builtin_amdgcn_mfma_f32_32x32x16_bf16(frA.v, vf1, poA1, 0, 0, 0);     \
      po2A = __builtin_amdgcn_mfma_f32_32x32x16_bf16(frA.v, one.v, po2A, 0, 0, 0);   \
      poB0 = __builtin_amdgcn_mfma_f32_32x32x16_bf16(frB.v, vf0, poB0, 0, 0, 0);     \
      poB1 = __builtin_amdgcn_mfma_f32_32x32x16_bf16(frB.v, vf1, poB1, 0, 0, 0);     \
      po2B = __builtin_amdgcn_mfma_f32_32x32x16_bf16(frB.v, one.v, po2B, 0, 0, 0);   \
    }
    PVSTEP(pA0, pB0, 0, 0)
    PVSTEP(pA0, pB0, 0, 1)
    PVSTEP(pA1, pB1, 32, 0)
    PVSTEP(pA1, pB1, 32, 1)
#undef PVSTEP
#undef CVT
  }

#define WRITEO(PO, PO2, QOFF, DT)                                                    \
  {                                                                                  \
    _Pragma("unroll")                                                                \
    for (int r = 0; r < 16; ++r) {                                                   \
      int qrow = (r & 3) + 8 * (r >> 2) + 4 * hi;                                    \
      float iv = 1.0f / PO2[r];                                                      \
      out[((size_t)b * LL + q0 + w * 64 + (QOFF) + qrow) * CC + h * DH + (DT) * 32 + lo] \
          = f2bf(PO[r] * iv);                                                        \
    }                                                                                \
  }
  WRITEO(poA0, po2A, 0, 0)
  WRITEO(poA1, po2A, 0, 1)
  WRITEO(poB0, po2B, 32, 0)
  WRITEO(poB1, po2B, 32, 1)
#undef WRITEO
}

extern "C" void kernel_launch(void* const* d_in, const int* in_sizes, int n_in,
                              void* d_out, int out_size, void* d_ws, size_t ws_size,
                              hipStream_t stream) {
  const float* x        = (const float*)d_in[0];
  const int*   mask     = (const int*)d_in[1];
  const float* dw_w     = (const float*)d_in[4];
  const float* pw_w     = (const float*)d_in[5];
  const float* pw_b     = (const float*)d_in[6];
  const float* cln_g    = (const float*)d_in[7];
  const float* cln_b    = (const float*)d_in[8];
  const float* w_kv     = (const float*)d_in[9];
  const float* b_kv     = (const float*)d_in[10];
  const float* w_q      = (const float*)d_in[11];
  const float* b_q      = (const float*)d_in[12];
  const float* ln_att_g = (const float*)d_in[13];
  const float* ln_att_b = (const float*)d_in[14];
  const float* w_ffd1   = (const float*)d_in[15];
  const float* b_ffd1   = (const float*)d_in[16];
  const float* w_ffd2   = (const float*)d_in[17];
  const float* b_ffd2   = (const float*)d_in[18];
  const float* ln_ffd_g = (const float*)d_in[19];
  const float* ln_ffd_b = (const float*)d_in[20];

  // Compact layout (68.5 MB, proven): [Wb: 9*n2 bf16][A0][A1][A2][A3], KQ = A1+A2.
  const size_t n2 = (size_t)CC * CC;
  size_t actElems = (size_t)BB * LL * CC;
  us* Wb = (us*)d_ws;
  us* pw_bf = Wb;
  us* kq_bf = Wb + 4 * n2;
  us* v_bf  = Wb + 6 * n2;
  us* f1_bf = Wb + 7 * n2;
  us* f2_bf = Wb + 8 * n2;
  us* A0 = Wb + 9 * n2;
  us* A1 = A0 + actElems;
  us* A2 = A1 + actElems;
  us* A3 = A2 + actElems;
  us* KQb = A1;

  long actB = (long)LL * CC;

  k_cvtW<<<2304, 256, 0, stream>>>(pw_w, w_kv, w_q, w_ffd1, w_ffd2, Wb);
  k_in_tr<<<dim3(8, 16, BB), 256, 0, stream>>>(x, A0);

  for (int i = 0; i < 4; ++i) {
    k_lndw<<<4096, 256, 0, stream>>>(A0, cln_g + i * CC, cln_b + i * CC,
                                     dw_w + (size_t)i * CC * KW, A3);
    k_gemm<1, 0, 0><<<dim3(8, 8, BB), 256, 0, stream>>>(
        A3, actB, pw_bf + (size_t)i * n2, 0, pw_b + i * CC, pw_b + i * CC,
        A0, 512, actB);
  }

  k_ln<<<4096, 256, 0, stream>>>(A0, ln_att_g, ln_att_b, A3);
  k_gemm<0, 0, 2><<<dim3(16, 8, BB), 256, 0, stream>>>(
      A3, actB, kq_bf, 0, b_kv, b_q, KQb, 1024, (long)LL * 1024);   // K|Q (B,L,1024)
  k_gemm<0, 0, 1><<<dim3(16, 4, BB), 256, 0, stream>>>(
      v_bf, 0, A3, actB, b_kv + CC, b_kv + CC, A0, 1024, actB);     // V (B,C,L)
  k_attn<<<dim3(4, NHEAD, BB), 256, 0, stream>>>(KQb, A0, mask, A3);

  k_ln<<<4096, 256, 0, stream>>>(A3, ln_ffd_g, ln_ffd_b, A0);
  k_gemm<1, 0, 0><<<dim3(8, 8, BB), 256, 0, stream>>>(
      A0, actB, f1_bf, 0, b_ffd1, b_ffd1, A1, 512, actB);
  k_gemm<0, 1, 1><<<dim3(16, 4, BB), 256, 0, stream>>>(
      f2_bf, 0, A1, actB, b_ffd2, b_ffd2, d_out, 1024, (long)CC * LL);
}

// Round 16
// 307.579 us; speedup vs baseline: 1.6770x; 1.1299x over previous
//
#include <hip/hip_runtime.h>
#include <math.h>

#define BB 16
#define CC 512
#define LL 1024
#define NHEAD 8
#define DH 64
#define KW 7

typedef unsigned short us;
typedef unsigned short us8 __attribute__((ext_vector_type(8)));
typedef unsigned short us4 __attribute__((ext_vector_type(4)));
typedef short mbf8 __attribute__((ext_vector_type(8)));
typedef float f32x4 __attribute__((ext_vector_type(4)));
typedef float f32x16 __attribute__((ext_vector_type(16)));

#define QSCALE 0.18033688f  /* 0.125 * log2(e) */

__device__ inline us f2bf(float f) {
  union { float f; unsigned int u; } v; v.f = f;
  unsigned int u = v.u;
  u += 0x7fffu + ((u >> 16) & 1u);
  return (us)(u >> 16);
}
__device__ inline float bf2f(us s) {
  union { unsigned int u; float f; } v; v.u = ((unsigned int)s) << 16;
  return v.f;
}
__device__ __forceinline__ float fexp2(float x) {
  float r;
  asm("v_exp_f32 %0, %1" : "=v"(r) : "v"(x));
  return r;
}

// global -> LDS direct 16B copy
__device__ __forceinline__ void gld16(const void* g, void* l) {
  __builtin_amdgcn_global_load_lds(
      (__attribute__((address_space(1))) unsigned int*)(uintptr_t)(g),
      (__attribute__((address_space(3))) unsigned int*)(unsigned int)(uintptr_t)(l),
      16, 0, 0);
}

// ---- weight fp32 -> bf16 pre-convert, 9 regions of CC*CC ----
// [0..4):pw_w  [4):w_kv K-rows  [5):w_q * QSCALE  [6):w_kv V-rows  [7):ffd1 [8):ffd2
__global__ __launch_bounds__(256) void k_cvtW(const float* __restrict__ pw,
                                              const float* __restrict__ wkv,
                                              const float* __restrict__ wq,
                                              const float* __restrict__ wf1,
                                              const float* __restrict__ wf2,
                                              us* __restrict__ dst) {
  int idx = blockIdx.x * 256 + threadIdx.x;
  int e = idx * 4;
  const int n2 = CC * CC;
  int r = e / n2, o = e - r * n2;
  const float* src; float sc = 1.0f;
  if (r < 4)       { src = pw + e; }
  else if (r == 4) { src = wkv + o; }
  else if (r == 5) { src = wq + o; sc = QSCALE; }
  else if (r == 6) { src = wkv + n2 + o; }
  else if (r == 7) { src = wf1 + o; }
  else             { src = wf2 + o; }
  float4 v = *(const float4*)src;
  us4 ov; ov[0] = f2bf(v.x * sc); ov[1] = f2bf(v.y * sc);
  ov[2] = f2bf(v.z * sc); ov[3] = f2bf(v.w * sc);
  *(us4*)(dst + e) = ov;
}

// ---- x (B,C,L) f32 -> Act (B,L,C) bf16 with timing signal ----
__global__ __launch_bounds__(256) void k_in_tr(const float* __restrict__ x,
                                               us* __restrict__ act) {
  __shared__ float xt[64][69];
  int t = threadIdx.x;
  int c0 = blockIdx.x * 64;
  int l0 = blockIdx.y * 64;
  int b  = blockIdx.z;
  {
    int r = t >> 2, lo2 = (t & 3) * 16;
    const float* src = x + ((size_t)b * CC + c0 + r) * LL + l0 + lo2;
#pragma unroll
    for (int q = 0; q < 4; ++q) {
      float4 v = *(const float4*)(src + q * 4);
      xt[r][lo2 + q * 4 + 0] = v.x; xt[r][lo2 + q * 4 + 1] = v.y;
      xt[r][lo2 + q * 4 + 2] = v.z; xt[r][lo2 + q * 4 + 3] = v.w;
    }
  }
  __syncthreads();
  const float log_inc = 9.210340371976184f / 255.0f;
  int lr = t >> 2, co = (t & 3) * 16;
  int l = l0 + lr;
  us obuf[16];
#pragma unroll
  for (int u = 0; u < 16; ++u) {
    int c = c0 + co + u;
    float inv = __expf(-(float)(c & 255) * log_inc);
    float st = (float)l * inv;
    float sg = (c < 256) ? sinf(st) : cosf(st);
    obuf[u] = f2bf(xt[co + u][lr] + sg);
  }
  us* dst = act + ((size_t)b * LL + l) * CC + c0 + co;
  *(us8*)dst = *(us8*)&obuf[0];
  *(us8*)(dst + 8) = *(us8*)&obuf[8];
}

// ---- row LayerNorm over C, (B,L,C) bf16 ----
__global__ __launch_bounds__(256) void k_ln(const us* __restrict__ in,
                                            const float* __restrict__ g,
                                            const float* __restrict__ bta,
                                            us* __restrict__ out) {
  int t = threadIdx.x;
  int lane = t & 63, w = t >> 6;
  size_t row = (size_t)blockIdx.x * 4 + w;
  const us* p = in + row * CC + lane * 8;
  us8 v = *(const us8*)p;
  float f[8]; float s = 0.f, ss = 0.f;
#pragma unroll
  for (int i = 0; i < 8; ++i) { f[i] = bf2f(v[i]); s += f[i]; ss += f[i] * f[i]; }
#pragma unroll
  for (int m = 1; m < 64; m <<= 1) { s += __shfl_xor(s, m); ss += __shfl_xor(ss, m); }
  float mean = s * (1.f / CC);
  float rstd = rsqrtf(ss * (1.f / CC) - mean * mean + 1e-5f);
  float4 g0 = *(const float4*)(g + lane * 8), g1 = *(const float4*)(g + lane * 8 + 4);
  float4 b0 = *(const float4*)(bta + lane * 8), b1 = *(const float4*)(bta + lane * 8 + 4);
  float gg[8] = {g0.x, g0.y, g0.z, g0.w, g1.x, g1.y, g1.z, g1.w};
  float bb2[8] = {b0.x, b0.y, b0.z, b0.w, b1.x, b1.y, b1.z, b1.w};
  us o[8];
#pragma unroll
  for (int i = 0; i < 8; ++i) o[i] = f2bf((f[i] - mean) * rstd * gg[i] + bb2[i]);
  *(us8*)(out + row * CC + lane * 8) = *(us8*)&o[0];
}

// ---- fused LayerNorm + depthwise conv K=7 along L, (B,L,C) bf16 ----
// 16 rows/block: stats computed once (22 slots), each thread covers 4
// consecutive rows -> 10-row tap window loaded once (10 loads vs 28).
__global__ __launch_bounds__(256) void k_lndw(const us* __restrict__ in,
                                              const float* __restrict__ g,
                                              const float* __restrict__ bln,
                                              const float* __restrict__ w,
                                              us* __restrict__ out) {
  __shared__ float wld[KW * CC];
  __shared__ float stm[24], str[24];
  int t = threadIdx.x;
  int lane = t & 63, wv = t >> 6;
  for (int i = t; i < CC * KW; i += 256) {
    int j = i >> 9, c2 = i & (CC - 1);
    wld[i] = w[c2 * KW + j];
  }
  int l0 = (blockIdx.x & 63) * 16;
  int b  = blockIdx.x >> 6;
  // stats for rows l0-3 .. l0+18 (slots 0..21)
#pragma unroll
  for (int i = 0; i < 6; ++i) {
    int slot = wv + i * 4;
    if (slot < 22) {
      int r = l0 - 3 + slot;
      float mean = 0.f, rstd = 0.f;
      if (r >= 0 && r < LL) {
        us8 v = *(const us8*)(in + ((size_t)b * LL + r) * CC + lane * 8);
        float s = 0.f, ss = 0.f;
#pragma unroll
        for (int u = 0; u < 8; ++u) { float f = bf2f(v[u]); s += f; ss += f * f; }
#pragma unroll
        for (int m = 1; m < 64; m <<= 1) { s += __shfl_xor(s, m); ss += __shfl_xor(ss, m); }
        mean = s * (1.f / CC);
        rstd = rsqrtf(ss * (1.f / CC) - mean * mean + 1e-5f);
      }
      if (lane == 0) { stm[slot] = mean; str[slot] = rstd; }
    }
  }
  __syncthreads();
  int c = lane * 8;
  int k0 = wv * 4;   // this thread's 4 rows: l0+k0 .. l0+k0+3
  float acc[4][8] = {}, ws[4][8] = {};
#pragma unroll
  for (int j = 0; j < 10; ++j) {
    int lj = l0 + k0 - 3 + j;
    if (lj < 0 || lj >= LL) continue;
    int slot = k0 + j;
    float mean = stm[slot], rstd = str[slot];
    us8 v = *(const us8*)(in + ((size_t)b * LL + lj) * CC + c);
    float nh[8];
#pragma unroll
    for (int u = 0; u < 8; ++u) nh[u] = (bf2f(v[u]) - mean) * rstd;
#pragma unroll
    for (int rr = 0; rr < 4; ++rr) {
      int jt = j - rr;
      if (jt >= 0 && jt < KW) {
        float4 w0 = *(const float4*)&wld[jt * CC + c];
        float4 w1 = *(const float4*)&wld[jt * CC + c + 4];
        float wj[8] = {w0.x, w0.y, w0.z, w0.w, w1.x, w1.y, w1.z, w1.w};
#pragma unroll
        for (int u = 0; u < 8; ++u) {
          acc[rr][u] += wj[u] * nh[u];
          ws[rr][u] += wj[u];
        }
      }
    }
  }
  float4 g0 = *(const float4*)(g + c), g1 = *(const float4*)(g + c + 4);
  float4 b0 = *(const float4*)(bln + c), b1 = *(const float4*)(bln + c + 4);
  float gg[8] = {g0.x, g0.y, g0.z, g0.w, g1.x, g1.y, g1.z, g1.w};
  float bb2[8] = {b0.x, b0.y, b0.z, b0.w, b1.x, b1.y, b1.z, b1.w};
#pragma unroll
  for (int rr = 0; rr < 4; ++rr) {
    int l = l0 + k0 + rr;
    us o[8];
#pragma unroll
    for (int u = 0; u < 8; ++u) o[u] = f2bf(gg[u] * acc[rr][u] + bb2[u] * ws[rr][u]);
    *(us8*)(out + ((size_t)b * LL + l) * CC + c) = *(us8*)&o[0];
  }
}

// ---- MFMA GEMM: 2-phase double-buffered, 128x64 tile (R11-proven) ----
// 4 waves each 64x32. LDS 48 KB. BIASMODE: 0=bias[col], 1=bias[row], 2=KQ.
template <int RELU, int F32OUT, int BIASMODE>
__global__ __launch_bounds__(256) void k_gemm(const us* __restrict__ A, long Ab,
                                              const us* __restrict__ Bm, long Bb,
                                              const float* __restrict__ bias,
                                              const float* __restrict__ bias2,
                                              void* __restrict__ outp,
                                              long orow, long obatch) {
  __shared__ __align__(16) us Ald[2][128 * 64];
  __shared__ __align__(16) us Bld[2][64 * 64];
  int t = threadIdx.x;
  int lane = t & 63, w = t >> 6;
  int wi = w >> 1, wj = w & 1;   // wave tile: rows 64*wi, cols 32*wj
  int gx = gridDim.x, gy = gridDim.y;
  int lin = blockIdx.x + gx * (blockIdx.y + gy * blockIdx.z);
  int nwg = gx * gy * gridDim.z;
  int swz = (lin & 7) * (nwg >> 3) + (lin >> 3);
  int bx = swz % gx; int rem = swz / gx; int by = rem % gy; int bz = rem / gy;
  int i0 = by * 128, j0 = bx * 64;
  const us* Ag = A + (size_t)bz * Ab + (size_t)i0 * 512;
  const us* Bg = Bm + (size_t)bz * Bb + (size_t)j0 * 512;
  int rr = lane >> 3, cc8 = (lane & 7) * 8;
  f32x4 acc[4][2];
  const f32x4 fz = {0.f, 0.f, 0.f, 0.f};
#pragma unroll
  for (int a = 0; a < 4; ++a)
#pragma unroll
    for (int c = 0; c < 2; ++c) acc[a][c] = fz;

#define STAGE(BUF, K0)                                                        \
  {                                                                           \
    _Pragma("unroll")                                                         \
    for (int it = 0; it < 4; ++it) {                                          \
      int ch = w * 4 + it;                                                    \
      gld16(Ag + (size_t)(ch * 8 + rr) * 512 + (K0) + cc8, &Ald[BUF][ch * 512]); \
    }                                                                         \
    _Pragma("unroll")                                                         \
    for (int it = 0; it < 2; ++it) {                                          \
      int ch = w * 2 + it;                                                    \
      gld16(Bg + (size_t)(ch * 8 + rr) * 512 + (K0) + cc8, &Bld[BUF][ch * 512]); \
    }                                                                         \
  }

  STAGE(0, 0)
#pragma unroll
  for (int tk = 0; tk < 8; ++tk) {
    int cur = tk & 1;
    __syncthreads();  // drains vmcnt: buffer `cur` staged; prev readers done
    if (tk < 7) STAGE(cur ^ 1, (tk + 1) * 64)  // flies under this tile's MFMAs
    mbf8 af[4][2], bfr[2][2];
#pragma unroll
    for (int fi = 0; fi < 4; ++fi)
#pragma unroll
      for (int kh = 0; kh < 2; ++kh)
        af[fi][kh] = *(const mbf8*)&Ald[cur][(wi * 64 + fi * 16 + (lane & 15)) * 64 + kh * 32 + (lane >> 4) * 8];
#pragma unroll
    for (int fj = 0; fj < 2; ++fj)
#pragma unroll
      for (int kh = 0; kh < 2; ++kh)
        bfr[fj][kh] = *(const mbf8*)&Bld[cur][(wj * 32 + fj * 16 + (lane & 15)) * 64 + kh * 32 + (lane >> 4) * 8];
#pragma unroll
    for (int fi = 0; fi < 4; ++fi)
#pragma unroll
      for (int fj = 0; fj < 2; ++fj)
#pragma unroll
        for (int kh = 0; kh < 2; ++kh)
          acc[fi][fj] = __builtin_amdgcn_mfma_f32_16x16x32_bf16(af[fi][kh], bfr[fj][kh], acc[fi][fj], 0, 0, 0);
  }
#undef STAGE

#pragma unroll
  for (int fi = 0; fi < 4; ++fi)
#pragma unroll
    for (int fj = 0; fj < 2; ++fj) {
      int col = j0 + wj * 32 + fj * 16 + (lane & 15);
      float bv;
      if (BIASMODE == 2) bv = (col < CC) ? bias[col] : bias2[col - CC] * QSCALE;
      else if (BIASMODE == 0) bv = bias[col];
#pragma unroll
      for (int r = 0; r < 4; ++r) {
        int row = i0 + wi * 64 + fi * 16 + (lane >> 4) * 4 + r;
        float bvr = (BIASMODE == 1) ? bias[row] : bv;
        float v = acc[fi][fj][r] + bvr;
        if (RELU) v = fmaxf(v, 0.f);
        size_t off = (size_t)bz * obatch + (size_t)row * orow + col;
        if (F32OUT) ((float*)outp)[off] = v;
        else        ((us*)outp)[off] = f2bf(v);
      }
    }
}

// ---- flash attention, swapped-QK 32x32; mask applied via MFMA bias (R10) ----
__global__ __launch_bounds__(256) void k_attn(const us* __restrict__ KQ,
                                              const us* __restrict__ Vb,
                                              const int* __restrict__ mask,
                                              us* __restrict__ out) {
  __shared__ __align__(16) us Kld[64][72];  // [k][d]
  __shared__ __align__(16) us Vld[64][72];  // [d][k]
  __shared__ unsigned int mbits[32];
  int t = threadIdx.x;
  int lane = t & 63, w = t >> 6;
  int lo = lane & 31, hi = lane >> 5;
  int lin = blockIdx.x + 8 * (blockIdx.y + 8 * blockIdx.z);
  int swz = (lin & 7) * 128 + (lin >> 3);
  int q0 = (swz & 7) * 128;
  int h = (swz >> 3) & 7;
  int b = swz >> 6;

#pragma unroll
  for (int j = 0; j < 4; ++j) {
    int k = w * 256 + j * 64 + lane;
    unsigned long long bl = __ballot(mask[(size_t)b * LL + k] != 0);
    if (lane == 0) {
      mbits[w * 8 + j * 2]     = (unsigned int)bl;
      mbits[w * 8 + j * 2 + 1] = (unsigned int)(bl >> 32);
    }
  }

  mbf8 qf[4];
  {
    const us* qp = KQ + ((size_t)b * LL + q0 + w * 32 + lo) * 1024 + 512 + h * DH + hi * 8;
#pragma unroll
    for (int ds = 0; ds < 4; ++ds) qf[ds] = *(const mbf8*)(qp + ds * 16);
  }

  union { int i[4]; mbf8 v; } one;
  one.i[0] = 0x3F803F80; one.i[1] = 0x3F803F80; one.i[2] = 0x3F803F80; one.i[3] = 0x3F803F80;

  int sr = t >> 2, sko = (t & 3) * 16;
  const us* pkbase = KQ + ((size_t)b * LL + sr) * 1024 + h * DH + sko;
  const us* pvbase = Vb + ((size_t)b * CC + h * DH + sr) * LL + sko;
  us8 kr0 = *(const us8*)pkbase, kr1 = *(const us8*)(pkbase + 8);
  us8 vr0 = *(const us8*)pvbase, vr1 = *(const us8*)(pvbase + 8);

  const f32x16 Z16 = {0,0,0,0,0,0,0,0,0,0,0,0,0,0,0,0};
  f32x16 po0 = Z16, po1 = Z16, po2 = Z16;

  for (int kt = 0; kt < 16; ++kt) {
    asm volatile("s_waitcnt lgkmcnt(0)" ::: "memory");
    __builtin_amdgcn_s_barrier();
    asm volatile("" ::: "memory");
    *(us8*)&Kld[sr][sko]     = kr0;  *(us8*)&Kld[sr][sko + 8] = kr1;
    *(us8*)&Vld[sr][sko]     = vr0;  *(us8*)&Vld[sr][sko + 8] = vr1;
    if (kt < 15) {
      const us* pk = pkbase + (size_t)(kt + 1) * 64 * 1024;
      const us* pv = pvbase + (kt + 1) * 64;
      kr0 = *(const us8*)pk; kr1 = *(const us8*)(pk + 8);
      vr0 = *(const us8*)pv; vr1 = *(const us8*)(pv + 8);
    }
    asm volatile("s_waitcnt lgkmcnt(0)" ::: "memory");
    __builtin_amdgcn_s_barrier();
    asm volatile("" ::: "memory");

    uint2 mbp = *(const uint2*)&mbits[kt * 2];
    unsigned int b0 = (mbp.x >> lo) & 1u;
    unsigned int b1 = (mbp.y >> lo) & 1u;
    union { int i[4]; mbf8 v; } ma0, ma1;
    ma0.i[0] = (hi == 0 && !b0) ? 0xC348 : 0;  // bf16(-200) in element 0
    ma0.i[1] = 0; ma0.i[2] = 0; ma0.i[3] = 0;
    ma1.i[0] = (hi == 0 && !b1) ? 0xC348 : 0;
    ma1.i[1] = 0; ma1.i[2] = 0; ma1.i[3] = 0;
    f32x16 s0 = __builtin_amdgcn_mfma_f32_32x32x16_bf16(ma0.v, one.v, Z16, 0, 0, 0);
    f32x16 s1 = __builtin_amdgcn_mfma_f32_32x32x16_bf16(ma1.v, one.v, Z16, 0, 0, 0);
#pragma unroll
    for (int ds = 0; ds < 4; ++ds) {
      mbf8 kf0 = *(const mbf8*)&Kld[lo][ds * 16 + hi * 8];
      mbf8 kf1 = *(const mbf8*)&Kld[32 + lo][ds * 16 + hi * 8];
      s0 = __builtin_amdgcn_mfma_f32_32x32x16_bf16(kf0, qf[ds], s0, 0, 0, 0);
      s1 = __builtin_amdgcn_mfma_f32_32x32x16_bf16(kf1, qf[ds], s1, 0, 0, 0);
    }
    float p0[16], p1[16];
#pragma unroll
    for (int r = 0; r < 16; ++r) { p0[r] = fexp2(s0[r]); p1[r] = fexp2(s1[r]); }

#define PVSTEP(P, KOFF, KS)                                                          \
    {                                                                                \
      int x0, x1, y0, y1;                                                            \
      asm("v_cvt_pk_bf16_f32 %0, %1, %2" : "=v"(x0) : "v"(P[8*KS+0]), "v"(P[8*KS+1])); \
      asm("v_cvt_pk_bf16_f32 %0, %1, %2" : "=v"(x1) : "v"(P[8*KS+2]), "v"(P[8*KS+3])); \
      asm("v_cvt_pk_bf16_f32 %0, %1, %2" : "=v"(y0) : "v"(P[8*KS+4]), "v"(P[8*KS+5])); \
      asm("v_cvt_pk_bf16_f32 %0, %1, %2" : "=v"(y1) : "v"(P[8*KS+6]), "v"(P[8*KS+7])); \
      asm("v_permlane32_swap_b32 %0, %1" : "+v"(x0), "+v"(y0));                      \
      asm("v_permlane32_swap_b32 %0, %1" : "+v"(x1), "+v"(y1));                      \
      union { int i[4]; mbf8 v; } fr;                                                \
      fr.i[0] = x0; fr.i[1] = x1; fr.i[2] = y0; fr.i[3] = y1;                        \
      mbf8 vf0 = *(const mbf8*)&Vld[lo][(KOFF) + (KS) * 16 + hi * 8];                \
      mbf8 vf1 = *(const mbf8*)&Vld[32 + lo][(KOFF) + (KS) * 16 + hi * 8];           \
      po0 = __builtin_amdgcn_mfma_f32_32x32x16_bf16(fr.v, vf0, po0, 0, 0, 0);        \
      po1 = __builtin_amdgcn_mfma_f32_32x32x16_bf16(fr.v, vf1, po1, 0, 0, 0);        \
      po2 = __builtin_amdgcn_mfma_f32_32x32x16_bf16(fr.v, one.v, po2, 0, 0, 0);      \
    }
    PVSTEP(p0, 0, 0)
    PVSTEP(p0, 0, 1)
    PVSTEP(p1, 32, 0)
    PVSTEP(p1, 32, 1)
#undef PVSTEP
  }

#define WRITEO(PO, DT)                                                               \
  {                                                                                  \
    _Pragma("unroll")                                                                \
    for (int r = 0; r < 16; ++r) {                                                   \
      int qrow = (r & 3) + 8 * (r >> 2) + 4 * hi;                                    \
      float iv = 1.0f / po2[r];                                                      \
      out[((size_t)b * LL + q0 + w * 32 + qrow) * CC + h * DH + (DT) * 32 + lo]      \
          = f2bf(PO[r] * iv);                                                        \
    }                                                                                \
  }
  WRITEO(po0, 0)
  WRITEO(po1, 1)
#undef WRITEO
}

extern "C" void kernel_launch(void* const* d_in, const int* in_sizes, int n_in,
                              void* d_out, int out_size, void* d_ws, size_t ws_size,
                              hipStream_t stream) {
  const float* x        = (const float*)d_in[0];
  const int*   mask     = (const int*)d_in[1];
  const float* dw_w     = (const float*)d_in[4];
  const float* pw_w     = (const float*)d_in[5];
  const float* pw_b     = (const float*)d_in[6];
  const float* cln_g    = (const float*)d_in[7];
  const float* cln_b    = (const float*)d_in[8];
  const float* w_kv     = (const float*)d_in[9];
  const float* b_kv     = (const float*)d_in[10];
  const float* w_q      = (const float*)d_in[11];
  const float* b_q      = (const float*)d_in[12];
  const float* ln_att_g = (const float*)d_in[13];
  const float* ln_att_b = (const float*)d_in[14];
  const float* w_ffd1   = (const float*)d_in[15];
  const float* b_ffd1   = (const float*)d_in[16];
  const float* w_ffd2   = (const float*)d_in[17];
  const float* b_ffd2   = (const float*)d_in[18];
  const float* ln_ffd_g = (const float*)d_in[19];
  const float* ln_ffd_b = (const float*)d_in[20];

  // Compact layout (68.5 MB, proven): [Wb: 9*n2 bf16][A0][A1][A2][A3], KQ = A1+A2.
  const size_t n2 = (size_t)CC * CC;
  size_t actElems = (size_t)BB * LL * CC;
  us* Wb = (us*)d_ws;
  us* pw_bf = Wb;
  us* kq_bf = Wb + 4 * n2;
  us* v_bf  = Wb + 6 * n2;
  us* f1_bf = Wb + 7 * n2;
  us* f2_bf = Wb + 8 * n2;
  us* A0 = Wb + 9 * n2;
  us* A1 = A0 + actElems;
  us* A2 = A1 + actElems;
  us* A3 = A2 + actElems;
  us* KQb = A1;

  long actB = (long)LL * CC;

  k_cvtW<<<2304, 256, 0, stream>>>(pw_w, w_kv, w_q, w_ffd1, w_ffd2, Wb);
  k_in_tr<<<dim3(8, 16, BB), 256, 0, stream>>>(x, A0);

  for (int i = 0; i < 4; ++i) {
    k_lndw<<<1024, 256, 0, stream>>>(A0, cln_g + i * CC, cln_b + i * CC,
                                     dw_w + (size_t)i * CC * KW, A3);
    k_gemm<1, 0, 0><<<dim3(8, 8, BB), 256, 0, stream>>>(
        A3, actB, pw_bf + (size_t)i * n2, 0, pw_b + i * CC, pw_b + i * CC,
        A0, 512, actB);
  }

  k_ln<<<4096, 256, 0, stream>>>(A0, ln_att_g, ln_att_b, A3);
  k_gemm<0, 0, 2><<<dim3(16, 8, BB), 256, 0, stream>>>(
      A3, actB, kq_bf, 0, b_kv, b_q, KQb, 1024, (long)LL * 1024);   // K|Q (B,L,1024)
  k_gemm<0, 0, 1><<<dim3(16, 4, BB), 256, 0, stream>>>(
      v_bf, 0, A3, actB, b_kv + CC, b_kv + CC, A0, 1024, actB);     // V (B,C,L)
  k_attn<<<dim3(8, NHEAD, BB), 256, 0, stream>>>(KQb, A0, mask, A3);

  k_ln<<<4096, 256, 0, stream>>>(A3, ln_ffd_g, ln_ffd_b, A0);
  k_gemm<1, 0, 0><<<dim3(8, 8, BB), 256, 0, stream>>>(
      A0, actB, f1_bf, 0, b_ffd1, b_ffd1, A1, 512, actB);
  k_gemm<0, 1, 1><<<dim3(16, 4, BB), 256, 0, stream>>>(
      f2_bf, 0, A1, actB, b_ffd2, b_ffd2, d_out, 1024, (long)CC * LL);
}